// Round 2
// baseline (541.337 us; speedup 1.0000x reference)
//
#include <hip/hip_runtime.h>
#include <math.h>

// Problem constants (from setup_inputs)
constexpr int Lc   = 4096;
constexpr int Bc   = 2;
constexpr int KNB  = 30;    // TOP_K
constexpr int NF   = 167;   // 16 pos + 144 rbf + 7 orient
constexpr int NFP  = 168;   // padded
constexpr int NC   = 128;   // output channels
constexpr int CHUNK = 56;   // 3 chunks of 56 cover 168

struct V3 { float x, y, z; };

__device__ __forceinline__ float sgnf(float v) {
    return (v > 0.f) ? 1.f : ((v < 0.f) ? -1.f : 0.f);
}

__device__ __forceinline__ unsigned long long umin64(unsigned long long a, unsigned long long b) {
    return a < b ? a : b;
}

// ---------------------------------------------------------------------------
// Kernel 1: masked distance + top-30 selection per row.
// One 256-thread block per (b,i). Exact JAX lax.top_k tie-breaking via
// (float_bits << 32 | index) u64 min-reduction (positive floats are
// bit-order monotone).
// EidxF: float-valued indices written into d_out tail (harness reads the
// whole output buffer as float32). EidxI: int copy in ws for edge_kernel.
// ---------------------------------------------------------------------------
__global__ __launch_bounds__(256) void topk_kernel(
    const float* __restrict__ Ca, const float* __restrict__ mask,
    float* __restrict__ Dn, float* __restrict__ EidxF, int* __restrict__ EidxI) {
    const int row = blockIdx.x;                 // b*L + i
    const int b = row >> 12, i = row & (Lc - 1);
    const float* CaB = Ca + (size_t)b * Lc * 3;
    const float* mB  = mask + (size_t)b * Lc;
    const float xi = CaB[i * 3 + 0], yi = CaB[i * 3 + 1], zi = CaB[i * 3 + 2];
    const float mi = mB[i];

    __shared__ float Dsh[Lc];
    __shared__ float redMax[4];
    __shared__ unsigned long long redK[4];

    const int t = threadIdx.x, lane = t & 63, wid = t >> 6;
    const int j0 = t * 16;

    float lmax = -1e30f;
#pragma unroll
    for (int u = 0; u < 16; ++u) {
        int j = j0 + u;
        float dx = CaB[j * 3 + 0] - xi;
        float dy = CaB[j * 3 + 1] - yi;
        float dz = CaB[j * 3 + 2] - zi;
        float d = sqrtf(dx * dx + dy * dy + dz * dz + 1e-6f);
        float m2 = mi * mB[j];
        float dm = m2 * d;
        Dsh[j] = dm;
        lmax = fmaxf(lmax, dm);
    }
    for (int off = 32; off; off >>= 1) lmax = fmaxf(lmax, __shfl_xor(lmax, off));
    if (lane == 0) redMax[wid] = lmax;
    __syncthreads();
    const float dmax = fmaxf(fmaxf(redMax[0], redMax[1]), fmaxf(redMax[2], redMax[3]));

    unsigned long long lkey = ~0ULL;
#pragma unroll
    for (int u = 0; u < 16; ++u) {
        int j = j0 + u;
        float m2 = mi * mB[j];
        float da = Dsh[j] + (1.f - m2) * dmax;   // D_adjust (identity when mask==1)
        Dsh[j] = da;
        unsigned long long k = ((unsigned long long)__float_as_uint(da) << 32) | (unsigned)j;
        lkey = umin64(lkey, k);
    }
    __syncthreads();

    for (int p = 0; p < KNB; ++p) {
        unsigned long long k = lkey;
        for (int off = 32; off; off >>= 1) k = umin64(k, __shfl_xor(k, off));
        if (lane == 0) redK[wid] = k;
        __syncthreads();
        unsigned long long w = umin64(umin64(redK[0], redK[1]), umin64(redK[2], redK[3]));
        int jw = (int)(w & 0xFFFFFFFFULL);
        if (t == 0) {
            EidxF[(size_t)row * KNB + p] = (float)jw;     // exact for j < 2^24
            EidxI[(size_t)row * KNB + p] = jw;
            Dn[(size_t)row * KNB + p] = __uint_as_float((unsigned)(w >> 32));
        }
        if ((jw >> 4) == t) {  // owner invalidates + rescans its 16
            Dsh[jw] = __uint_as_float(0x7f800000u);
            unsigned long long nk = ~0ULL;
#pragma unroll
            for (int u = 0; u < 16; ++u) {
                int j = j0 + u;
                unsigned long long kk =
                    ((unsigned long long)__float_as_uint(Dsh[j]) << 32) | (unsigned)j;
                nk = umin64(nk, kk);
            }
            lkey = nk;
        }
        __syncthreads();
    }
}

// ---------------------------------------------------------------------------
// Kernel 2: per-node orientation frame O (9 floats), faithful to reference
// (bond-length mask 3.6..4.0 strict, normalize with max(norm,1e-12)).
// Valid for l in [1, L-3]; zero otherwise (pad 1 front, 2 back).
// ---------------------------------------------------------------------------
__device__ __forceinline__ V3 unit_seg(float dx, float dy, float dz) {
    float n = sqrtf(dx * dx + dy * dy + dz * dz);
    float m = (n > 3.6f && n < 4.0f) ? 1.f : 0.f;
    float nn = fmaxf(m * n, 1e-12f);
    V3 r; r.x = dx * m / nn; r.y = dy * m / nn; r.z = dz * m / nn;
    return r;
}

__global__ void orient_kernel(const float* __restrict__ Ca, float* __restrict__ O) {
    int idx = blockIdx.x * blockDim.x + threadIdx.x;
    if (idx >= Bc * Lc) return;
    int b = idx >> 12, l = idx & (Lc - 1);
    float* o = O + (size_t)idx * 9;
    if (l < 1 || l >= Lc - 2) {
#pragma unroll
        for (int q = 0; q < 9; ++q) o[q] = 0.f;
        return;
    }
    const float* C = Ca + ((size_t)b * Lc + (l - 1)) * 3;
    float ax = C[0], ay = C[1], az = C[2];
    float bx = C[3], by = C[4], bz = C[5];
    float cx = C[6], cy = C[7], cz = C[8];
    V3 u2 = unit_seg(bx - ax, by - ay, bz - az);
    V3 u1 = unit_seg(cx - bx, cy - by, cz - bz);
    // n2 = normalize(cross(u2,u1))
    float nx = u2.y * u1.z - u2.z * u1.y;
    float ny = u2.z * u1.x - u2.x * u1.z;
    float nz = u2.x * u1.y - u2.y * u1.x;
    float nn = fmaxf(sqrtf(nx * nx + ny * ny + nz * nz), 1e-12f);
    nx /= nn; ny /= nn; nz /= nn;
    // o1 = normalize(u2-u1)
    float ox = u2.x - u1.x, oy = u2.y - u1.y, oz = u2.z - u1.z;
    float on = fmaxf(sqrtf(ox * ox + oy * oy + oz * oz), 1e-12f);
    ox /= on; oy /= on; oz /= on;
    // row2 = cross(o1, n2)
    float rx = oy * nz - oz * ny;
    float ry = oz * nx - ox * nz;
    float rz = ox * ny - oy * nx;
    o[0] = ox; o[1] = oy; o[2] = oz;
    o[3] = nx; o[4] = ny; o[5] = nz;
    o[6] = rx; o[7] = ry; o[8] = rz;
}

// ---------------------------------------------------------------------------
// Kernel 3: fused per-edge features + (167x128) matvec + LayerNorm.
// One 256-thread block per (b,i) row of 30 edges.
// ---------------------------------------------------------------------------
__global__ __launch_bounds__(256) void edge_kernel(
    const float* __restrict__ Ca, const int* __restrict__ ridx,
    const int* __restrict__ clab, const float* __restrict__ pos_W,
    const float* __restrict__ pos_b, const float* __restrict__ edge_W,
    const float* __restrict__ ln_g, const float* __restrict__ ln_b,
    const float* __restrict__ Dn, const int* __restrict__ EidxI,
    const float* __restrict__ Omat, float* __restrict__ outE) {
    const int row = blockIdx.x;                 // b*L + i
    const int b = row >> 12, i = row & (Lc - 1);
    const int tid = threadIdx.x, lane = tid & 63, wid = tid >> 6;

    __shared__ __align__(16) float Fsh[32][NFP];      // 21.5 KB (rows 30,31 zero)
    __shared__ __align__(16) float Wc[CHUNK][NC];     // 28.7 KB

    const float* CaB = Ca + (size_t)b * Lc * 3;

    // --- Phase A: features (lanes 0..29 of wave 0), zero-pad (lanes 30..63),
    //              stage W chunk 0 (waves 1..3) ---
    if (tid < 30) {
        const int e = tid;
        const int j = EidxI[(size_t)row * KNB + e];
        // node-shifted coordinates with zero padding
        V3 Ai0, Ai1, Ai2, Bj0, Bj1, Bj2;
        Ai1.x = CaB[i * 3]; Ai1.y = CaB[i * 3 + 1]; Ai1.z = CaB[i * 3 + 2];
        Bj1.x = CaB[j * 3]; Bj1.y = CaB[j * 3 + 1]; Bj1.z = CaB[j * 3 + 2];
        if (i >= 1) { Ai0.x = CaB[(i-1)*3]; Ai0.y = CaB[(i-1)*3+1]; Ai0.z = CaB[(i-1)*3+2]; }
        else        { Ai0.x = 0.f; Ai0.y = 0.f; Ai0.z = 0.f; }
        if (i < Lc-1){ Ai2.x = CaB[(i+1)*3]; Ai2.y = CaB[(i+1)*3+1]; Ai2.z = CaB[(i+1)*3+2]; }
        else        { Ai2.x = 0.f; Ai2.y = 0.f; Ai2.z = 0.f; }
        if (j >= 1) { Bj0.x = CaB[(j-1)*3]; Bj0.y = CaB[(j-1)*3+1]; Bj0.z = CaB[(j-1)*3+2]; }
        else        { Bj0.x = 0.f; Bj0.y = 0.f; Bj0.z = 0.f; }
        if (j < Lc-1){ Bj2.x = CaB[(j+1)*3]; Bj2.y = CaB[(j+1)*3+1]; Bj2.z = CaB[(j+1)*3+2]; }
        else        { Bj2.x = 0.f; Bj2.y = 0.f; Bj2.z = 0.f; }

        // positional embedding: one_hot(d) @ pos_W + pos_b == pos_W[d] + pos_b
        int off = ridx[(size_t)b * Lc + i] - ridx[(size_t)b * Lc + j];
        int ec = (clab[(size_t)b * Lc + i] == clab[(size_t)b * Lc + j]) ? 1 : 0;
        int d = ec ? min(max(off + 32, 0), 64) : 65;
#pragma unroll
        for (int c = 0; c < 16; ++c) Fsh[e][c] = pos_W[d * 16 + c] + pos_b[c];

        // RBF helper
        auto putRBF = [&](int blk, float D) {
#pragma unroll
            for (int m = 0; m < 16; ++m) {
                float mu = 2.f + (20.f / 15.f) * (float)m;
                float z = (D - mu) * (1.f / 1.25f);
                Fsh[e][16 + blk * 16 + m] = expf(-z * z);
            }
        };
        auto dst = [](V3 a, V3 bb) {
            float dx = a.x - bb.x, dy = a.y - bb.y, dz = a.z - bb.z;
            return sqrtf(dx * dx + dy * dy + dz * dz + 1e-6f);
        };
        putRBF(0, Dn[(size_t)row * KNB + e]);
        putRBF(1, dst(Ai0, Bj0));
        putRBF(2, dst(Ai2, Bj2));
        putRBF(3, dst(Ai0, Bj1));
        putRBF(4, dst(Ai0, Bj2));
        putRBF(5, dst(Ai1, Bj0));
        putRBF(6, dst(Ai1, Bj2));
        putRBF(7, dst(Ai2, Bj0));
        putRBF(8, dst(Ai2, Bj1));

        // orientation features: dU (3) + Q (4)
        const float* Om = Omat + (size_t)row * 9;
        const float* On = Omat + ((size_t)b * Lc + j) * 9;
        float dvx = Bj1.x - Ai1.x, dvy = Bj1.y - Ai1.y, dvz = Bj1.z - Ai1.z;
        float u0 = Om[0] * dvx + Om[1] * dvy + Om[2] * dvz;
        float u1 = Om[3] * dvx + Om[4] * dvy + Om[5] * dvz;
        float u2 = Om[6] * dvx + Om[7] * dvy + Om[8] * dvz;
        float un = fmaxf(sqrtf(u0 * u0 + u1 * u1 + u2 * u2), 1e-12f);
        Fsh[e][160] = u0 / un; Fsh[e][161] = u1 / un; Fsh[e][162] = u2 / un;

        float R[3][3];
#pragma unroll
        for (int a = 0; a < 3; ++a)
#pragma unroll
            for (int m = 0; m < 3; ++m)
                R[a][m] = Om[0 * 3 + a] * On[0 * 3 + m] +
                          Om[1 * 3 + a] * On[1 * 3 + m] +
                          Om[2 * 3 + a] * On[2 * 3 + m];
        float Rxx = R[0][0], Ryy = R[1][1], Rzz = R[2][2];
        float m0 = 0.5f * sqrtf(fabsf(1.f + Rxx - Ryy - Rzz));
        float m1 = 0.5f * sqrtf(fabsf(1.f - Rxx + Ryy - Rzz));
        float m2 = 0.5f * sqrtf(fabsf(1.f - Rxx - Ryy + Rzz));
        float qx = sgnf(R[2][1] - R[1][2]) * m0;
        float qy = sgnf(R[0][2] - R[2][0]) * m1;
        float qz = sgnf(R[1][0] - R[0][1]) * m2;
        float qw = sqrtf(fmaxf(0.f, 1.f + Rxx + Ryy + Rzz)) * 0.5f;
        float qn = fmaxf(sqrtf(qx * qx + qy * qy + qz * qz + qw * qw), 1e-12f);
        Fsh[e][163] = qx / qn; Fsh[e][164] = qy / qn;
        Fsh[e][165] = qz / qn; Fsh[e][166] = qw / qn;
        Fsh[e][167] = 0.f;
    } else if (tid < 64) {
        // zero pad rows 30,31
        for (int q = tid - 30; q < 2 * NFP; q += 34)
            (&Fsh[30][0])[q] = 0.f;
    } else {
        // stage W chunk 0
        for (int idx = tid - 64; idx < CHUNK * NC; idx += 192) {
            int t = idx >> 7, c = idx & (NC - 1);
            Wc[t][c] = (t < NF) ? edge_W[(size_t)t * NC + c] : 0.f;
        }
    }
    __syncthreads();

    // --- Phase B: matvec, register-blocked 8 edges x 2 channels per lane ---
    const int e0 = wid * 8;
    float acc[8][2];
#pragma unroll
    for (int e = 0; e < 8; ++e) { acc[e][0] = 0.f; acc[e][1] = 0.f; }

    for (int ch = 0; ch < 3; ++ch) {
        if (ch) {
            __syncthreads();
            const int T0 = ch * CHUNK;
            for (int idx = tid; idx < CHUNK * NC; idx += 256) {
                int t = idx >> 7, c = idx & (NC - 1);
                Wc[t][c] = (T0 + t < NF) ? edge_W[(size_t)(T0 + t) * NC + c] : 0.f;
            }
            __syncthreads();
        }
        const int T0 = ch * CHUNK;
        for (int tt = 0; tt < CHUNK; tt += 4) {
            float w00 = Wc[tt + 0][lane], w01 = Wc[tt + 0][lane + 64];
            float w10 = Wc[tt + 1][lane], w11 = Wc[tt + 1][lane + 64];
            float w20 = Wc[tt + 2][lane], w21 = Wc[tt + 2][lane + 64];
            float w30 = Wc[tt + 3][lane], w31 = Wc[tt + 3][lane + 64];
#pragma unroll
            for (int e = 0; e < 8; ++e) {
                float4 f = *(const float4*)&Fsh[e0 + e][T0 + tt];
                acc[e][0] = fmaf(f.x, w00, acc[e][0]);
                acc[e][1] = fmaf(f.x, w01, acc[e][1]);
                acc[e][0] = fmaf(f.y, w10, acc[e][0]);
                acc[e][1] = fmaf(f.y, w11, acc[e][1]);
                acc[e][0] = fmaf(f.z, w20, acc[e][0]);
                acc[e][1] = fmaf(f.z, w21, acc[e][1]);
                acc[e][0] = fmaf(f.w, w30, acc[e][0]);
                acc[e][1] = fmaf(f.w, w31, acc[e][1]);
            }
        }
    }

    // --- Phase C: LayerNorm (wave-local: each wave owns full 128 channels
    //              of its 8 edges) + store ---
    const float g0 = ln_g[lane], g1 = ln_g[lane + 64];
    const float bb0 = ln_b[lane], bb1 = ln_b[lane + 64];
#pragma unroll
    for (int e = 0; e < 8; ++e) {
        int eg = e0 + e;
        if (eg >= KNB) break;
        float v0 = acc[e][0], v1 = acc[e][1];
        float s = v0 + v1;
        float q = v0 * v0 + v1 * v1;
        for (int off = 32; off; off >>= 1) {
            s += __shfl_xor(s, off);
            q += __shfl_xor(q, off);
        }
        float mean = s * (1.f / 128.f);
        float var = q * (1.f / 128.f) - mean * mean;
        float inv = 1.f / sqrtf(var + 1e-5f);
        size_t base = ((size_t)row * KNB + eg) * NC;
        outE[base + lane]      = (v0 - mean) * inv * g0 + bb0;
        outE[base + lane + 64] = (v1 - mean) * inv * g1 + bb1;
    }
}

// ---------------------------------------------------------------------------
extern "C" void kernel_launch(void* const* d_in, const int* in_sizes, int n_in,
                              void* d_out, int out_size, void* d_ws, size_t ws_size,
                              hipStream_t stream) {
    const float* Ca     = (const float*)d_in[0];
    const float* mask   = (const float*)d_in[1];
    const int*   ridx   = (const int*)d_in[2];
    const int*   clab   = (const int*)d_in[3];
    const float* pos_W  = (const float*)d_in[4];
    const float* pos_b  = (const float*)d_in[5];
    const float* edge_W = (const float*)d_in[6];
    const float* ln_g   = (const float*)d_in[7];
    const float* ln_b   = (const float*)d_in[8];

    float* outE  = (float*)d_out;
    float* EidxF = outE + (size_t)Bc * Lc * KNB * NC;   // output 1 (as float values)

    float* Dn    = (float*)d_ws;                        // B*L*30 floats
    float* Omat  = Dn + (size_t)Bc * Lc * KNB;          // B*L*9 floats
    int*   EidxI = (int*)(Omat + (size_t)Bc * Lc * 9);  // B*L*30 ints

    const int rows = Bc * Lc;
    topk_kernel<<<rows, 256, 0, stream>>>(Ca, mask, Dn, EidxF, EidxI);
    orient_kernel<<<(rows + 255) / 256, 256, 0, stream>>>(Ca, Omat);
    edge_kernel<<<rows, 256, 0, stream>>>(Ca, ridx, clab, pos_W, pos_b, edge_W,
                                          ln_g, ln_b, Dn, EidxI, Omat, outE);
}

// Round 3
// 358.353 us; speedup vs baseline: 1.5106x; 1.5106x over previous
//
#include <hip/hip_runtime.h>
#include <math.h>

// Problem constants (from setup_inputs)
constexpr int Lc   = 4096;
constexpr int Bc   = 2;
constexpr int KNB  = 30;    // TOP_K
constexpr int NF   = 167;   // 16 pos + 144 rbf + 7 orient
constexpr int NC   = 128;   // output channels
constexpr int KP   = 200;   // padded K stride (bf16 elems) -> 400B row stride
constexpr int NKT  = 6;     // K-tiles of 32 (192 >= 167)

typedef __attribute__((ext_vector_type(8))) short bf16x8;
typedef __attribute__((ext_vector_type(4))) float f32x4;

struct V3 { float x, y, z; };

__device__ __forceinline__ float sgnf(float v) {
    return (v > 0.f) ? 1.f : ((v < 0.f) ? -1.f : 0.f);
}
__device__ __forceinline__ unsigned long long umin64(unsigned long long a, unsigned long long b) {
    return a < b ? a : b;
}
__device__ __forceinline__ void splitbf(float v, unsigned short& h, unsigned short& l) {
    unsigned u = __float_as_uint(v);
    h = (unsigned short)(u >> 16);                       // truncated bf16 hi
    float fh = __uint_as_float((unsigned)h << 16);
    l = (unsigned short)(__float_as_uint(v - fh) >> 16); // bf16 of residual
}

// ---------------------------------------------------------------------------
// Kernel 0: pack edge_W (167x128 f32) into MFMA-fragment-ordered bf16 hi/lo.
// Fragment layout for mfma_f32_16x16x32_bf16 B-operand: lane l holds
// B[k = (l>>4)*8 + j][n = l&15], j=0..7. Pack index: ((kt*8+nt)*64+lane)*8+j.
// ---------------------------------------------------------------------------
__global__ void pack_kernel(const float* __restrict__ W,
                            unsigned short* __restrict__ Wh,
                            unsigned short* __restrict__ Wl) {
    int t = blockIdx.x * blockDim.x + threadIdx.x;   // 0 .. NKT*8*64
    if (t >= NKT * 8 * 64) return;
    int lane = t & 63, nt = (t >> 6) & 7, kt = t >> 9;
    int n = nt * 16 + (lane & 15);
    int kbase = kt * 32 + (lane >> 4) * 8;
    __align__(16) unsigned short h[8], l[8];
#pragma unroll
    for (int j = 0; j < 8; ++j) {
        int k = kbase + j;
        float v = (k < NF) ? W[(size_t)k * NC + n] : 0.f;
        splitbf(v, h[j], l[j]);
    }
    size_t o = (size_t)t * 8;
    *(bf16x8*)(Wh + o) = *(const bf16x8*)h;
    *(bf16x8*)(Wl + o) = *(const bf16x8*)l;
}

// ---------------------------------------------------------------------------
// Kernel 1: masked distance + top-30 selection per row (unchanged from R2).
// ---------------------------------------------------------------------------
__global__ __launch_bounds__(256) void topk_kernel(
    const float* __restrict__ Ca, const float* __restrict__ mask,
    float* __restrict__ Dn, float* __restrict__ EidxF, int* __restrict__ EidxI) {
    const int row = blockIdx.x;                 // b*L + i
    const int b = row >> 12, i = row & (Lc - 1);
    const float* CaB = Ca + (size_t)b * Lc * 3;
    const float* mB  = mask + (size_t)b * Lc;
    const float xi = CaB[i * 3 + 0], yi = CaB[i * 3 + 1], zi = CaB[i * 3 + 2];
    const float mi = mB[i];

    __shared__ float Dsh[Lc];
    __shared__ float redMax[4];
    __shared__ unsigned long long redK[4];

    const int t = threadIdx.x, lane = t & 63, wid = t >> 6;
    const int j0 = t * 16;

    float lmax = -1e30f;
#pragma unroll
    for (int u = 0; u < 16; ++u) {
        int j = j0 + u;
        float dx = CaB[j * 3 + 0] - xi;
        float dy = CaB[j * 3 + 1] - yi;
        float dz = CaB[j * 3 + 2] - zi;
        float d = sqrtf(dx * dx + dy * dy + dz * dz + 1e-6f);
        float m2 = mi * mB[j];
        float dm = m2 * d;
        Dsh[j] = dm;
        lmax = fmaxf(lmax, dm);
    }
    for (int off = 32; off; off >>= 1) lmax = fmaxf(lmax, __shfl_xor(lmax, off));
    if (lane == 0) redMax[wid] = lmax;
    __syncthreads();
    const float dmax = fmaxf(fmaxf(redMax[0], redMax[1]), fmaxf(redMax[2], redMax[3]));

    unsigned long long lkey = ~0ULL;
#pragma unroll
    for (int u = 0; u < 16; ++u) {
        int j = j0 + u;
        float m2 = mi * mB[j];
        float da = Dsh[j] + (1.f - m2) * dmax;
        Dsh[j] = da;
        unsigned long long k = ((unsigned long long)__float_as_uint(da) << 32) | (unsigned)j;
        lkey = umin64(lkey, k);
    }
    __syncthreads();

    for (int p = 0; p < KNB; ++p) {
        unsigned long long k = lkey;
        for (int off = 32; off; off >>= 1) k = umin64(k, __shfl_xor(k, off));
        if (lane == 0) redK[wid] = k;
        __syncthreads();
        unsigned long long w = umin64(umin64(redK[0], redK[1]), umin64(redK[2], redK[3]));
        int jw = (int)(w & 0xFFFFFFFFULL);
        if (t == 0) {
            EidxF[(size_t)row * KNB + p] = (float)jw;
            EidxI[(size_t)row * KNB + p] = jw;
            Dn[(size_t)row * KNB + p] = __uint_as_float((unsigned)(w >> 32));
        }
        if ((jw >> 4) == t) {
            Dsh[jw] = __uint_as_float(0x7f800000u);
            unsigned long long nk = ~0ULL;
#pragma unroll
            for (int u = 0; u < 16; ++u) {
                int j = j0 + u;
                unsigned long long kk =
                    ((unsigned long long)__float_as_uint(Dsh[j]) << 32) | (unsigned)j;
                nk = umin64(nk, kk);
            }
            lkey = nk;
        }
        __syncthreads();
    }
}

// ---------------------------------------------------------------------------
// Kernel 2: per-node orientation frame O (unchanged from R2).
// ---------------------------------------------------------------------------
__device__ __forceinline__ V3 unit_seg(float dx, float dy, float dz) {
    float n = sqrtf(dx * dx + dy * dy + dz * dz);
    float m = (n > 3.6f && n < 4.0f) ? 1.f : 0.f;
    float nn = fmaxf(m * n, 1e-12f);
    V3 r; r.x = dx * m / nn; r.y = dy * m / nn; r.z = dz * m / nn;
    return r;
}

__global__ void orient_kernel(const float* __restrict__ Ca, float* __restrict__ O) {
    int idx = blockIdx.x * blockDim.x + threadIdx.x;
    if (idx >= Bc * Lc) return;
    int b = idx >> 12, l = idx & (Lc - 1);
    float* o = O + (size_t)idx * 9;
    if (l < 1 || l >= Lc - 2) {
#pragma unroll
        for (int q = 0; q < 9; ++q) o[q] = 0.f;
        return;
    }
    const float* C = Ca + ((size_t)b * Lc + (l - 1)) * 3;
    float ax = C[0], ay = C[1], az = C[2];
    float bx = C[3], by = C[4], bz = C[5];
    float cx = C[6], cy = C[7], cz = C[8];
    V3 u2 = unit_seg(bx - ax, by - ay, bz - az);
    V3 u1 = unit_seg(cx - bx, cy - by, cz - bz);
    float nx = u2.y * u1.z - u2.z * u1.y;
    float ny = u2.z * u1.x - u2.x * u1.z;
    float nz = u2.x * u1.y - u2.y * u1.x;
    float nn = fmaxf(sqrtf(nx * nx + ny * ny + nz * nz), 1e-12f);
    nx /= nn; ny /= nn; nz /= nn;
    float ox = u2.x - u1.x, oy = u2.y - u1.y, oz = u2.z - u1.z;
    float on = fmaxf(sqrtf(ox * ox + oy * oy + oz * oz), 1e-12f);
    ox /= on; oy /= on; oz /= on;
    float rx = oy * nz - oz * ny;
    float ry = oz * nx - ox * nz;
    float rz = ox * ny - oy * nx;
    o[0] = ox; o[1] = oy; o[2] = oz;
    o[3] = nx; o[4] = ny; o[5] = nz;
    o[6] = rx; o[7] = ry; o[8] = rz;
}

// ---------------------------------------------------------------------------
// Kernel 3: fused per-edge features (bf16 hi/lo in LDS) + MFMA matmul
// (32x128 = [32x192]@[192x128], split-bf16 3-product) + LayerNorm.
// One 256-thread block (4 waves) per (b,i) row of 30 edges.
// ---------------------------------------------------------------------------
__global__ __launch_bounds__(256) void edge_kernel(
    const float* __restrict__ Ca, const int* __restrict__ ridx,
    const int* __restrict__ clab, const float* __restrict__ pos_W,
    const float* __restrict__ pos_b,
    const unsigned short* __restrict__ Wh, const unsigned short* __restrict__ Wl,
    const float* __restrict__ ln_g, const float* __restrict__ ln_b,
    const float* __restrict__ Dn, const int* __restrict__ EidxI,
    const float* __restrict__ Omat, float* __restrict__ outE) {
    const int row = blockIdx.x;                 // b*L + i
    const int b = row >> 12, i = row & (Lc - 1);
    const int tid = threadIdx.x, lane = tid & 63, w = tid >> 6;

    __shared__ __align__(16) unsigned short Fh[32][KP];   // 12.5 KB
    __shared__ __align__(16) unsigned short Fl[32][KP];   // 12.5 KB
    __shared__ __align__(16) float Esh[32][132];          // 16.5 KB
    __shared__ int Ej[32];

    const float* CaB = Ca + (size_t)b * Lc * 3;

    // --- zero-fill feature LDS (padding must be 0) + load neighbor idx ---
    {
        unsigned* z1 = (unsigned*)&Fh[0][0];
        unsigned* z2 = (unsigned*)&Fl[0][0];
        for (int q = tid; q < 32 * KP / 2; q += 256) { z1[q] = 0u; z2[q] = 0u; }
        if (tid < KNB) Ej[tid] = EidxI[(size_t)row * KNB + tid];
    }
    __syncthreads();

    // --- feature build: 330 tasks of ~16 features over 256 threads ---
    auto putF = [&](int e, int k, float v) {
        unsigned short h, l;
        splitbf(v, h, l);
        Fh[e][k] = h; Fl[e][k] = l;
    };
    auto loadC = [&](int n) {
        V3 r;
        if (n >= 0 && n < Lc) { r.x = CaB[n*3]; r.y = CaB[n*3+1]; r.z = CaB[n*3+2]; }
        else { r.x = 0.f; r.y = 0.f; r.z = 0.f; }
        return r;
    };
    // rbf pair tables (indexed by g=2..9): shift in {0,1,2} => n-1+shift
    const int pa_t[10] = {0,0,0,2,0,0,1,1,2,2};
    const int pb_t[10] = {0,0,0,2,1,2,0,2,0,1};

    for (int task = tid; task < 330; task += 256) {
        int e = task % 30;
        int g = task / 30;
        int j = Ej[e];
        if (g == 0) {
            // positional: one_hot(d)@pos_W + pos_b == pos_W[d] + pos_b
            int off = ridx[(size_t)b * Lc + i] - ridx[(size_t)b * Lc + j];
            int ec = (clab[(size_t)b * Lc + i] == clab[(size_t)b * Lc + j]) ? 1 : 0;
            int d = ec ? min(max(off + 32, 0), 64) : 65;
#pragma unroll
            for (int c = 0; c < 16; ++c) putF(e, c, pos_W[d * 16 + c] + pos_b[c]);
        } else if (g < 10) {
            float D;
            if (g == 1) {
                D = Dn[(size_t)row * KNB + e];
            } else {
                V3 A = loadC(i - 1 + pa_t[g]);
                V3 B = loadC(j - 1 + pb_t[g]);
                float dx = A.x - B.x, dy = A.y - B.y, dz = A.z - B.z;
                D = sqrtf(dx * dx + dy * dy + dz * dz + 1e-6f);
            }
            int k0 = 16 * g;
#pragma unroll
            for (int m = 0; m < 16; ++m) {
                float mu = 2.f + (20.f / 15.f) * (float)m;
                float z = (D - mu) * (1.f / 1.25f);
                putF(e, k0 + m, __expf(-z * z));
            }
        } else {
            // orientation: dU (3) + Q (4)
            const float* Om = Omat + (size_t)row * 9;
            const float* On = Omat + ((size_t)b * Lc + j) * 9;
            V3 Ai = loadC(i), Bj = loadC(j);
            float dvx = Bj.x - Ai.x, dvy = Bj.y - Ai.y, dvz = Bj.z - Ai.z;
            float u0 = Om[0] * dvx + Om[1] * dvy + Om[2] * dvz;
            float u1 = Om[3] * dvx + Om[4] * dvy + Om[5] * dvz;
            float u2 = Om[6] * dvx + Om[7] * dvy + Om[8] * dvz;
            float un = fmaxf(sqrtf(u0 * u0 + u1 * u1 + u2 * u2), 1e-12f);
            putF(e, 160, u0 / un); putF(e, 161, u1 / un); putF(e, 162, u2 / un);
            float R[3][3];
#pragma unroll
            for (int a = 0; a < 3; ++a)
#pragma unroll
                for (int m = 0; m < 3; ++m)
                    R[a][m] = Om[0 * 3 + a] * On[0 * 3 + m] +
                              Om[1 * 3 + a] * On[1 * 3 + m] +
                              Om[2 * 3 + a] * On[2 * 3 + m];
            float Rxx = R[0][0], Ryy = R[1][1], Rzz = R[2][2];
            float m0 = 0.5f * sqrtf(fabsf(1.f + Rxx - Ryy - Rzz));
            float m1 = 0.5f * sqrtf(fabsf(1.f - Rxx + Ryy - Rzz));
            float m2 = 0.5f * sqrtf(fabsf(1.f - Rxx - Ryy + Rzz));
            float qx = sgnf(R[2][1] - R[1][2]) * m0;
            float qy = sgnf(R[0][2] - R[2][0]) * m1;
            float qz = sgnf(R[1][0] - R[0][1]) * m2;
            float qw = sqrtf(fmaxf(0.f, 1.f + Rxx + Ryy + Rzz)) * 0.5f;
            float qn = fmaxf(sqrtf(qx * qx + qy * qy + qz * qz + qw * qw), 1e-12f);
            putF(e, 163, qx / qn); putF(e, 164, qy / qn);
            putF(e, 165, qz / qn); putF(e, 166, qw / qn);
        }
    }
    __syncthreads();

    // --- MFMA phase: wave w owns N columns [w*32, w*32+32) ---
    // A-frag: lane holds A[row=l&15][k=(l>>4)*8+j]; C/D: col=l&15, row=(l>>4)*4+r
    const int arow = lane & 15, agrp = lane >> 4;
    const int ng0 = w * 2;  // global 16-col tile indices ng0, ng0+1
    f32x4 acc[2][2];
#pragma unroll
    for (int m = 0; m < 2; ++m)
#pragma unroll
        for (int n = 0; n < 2; ++n) acc[m][n] = (f32x4){0.f, 0.f, 0.f, 0.f};

    const bf16x8* WhF = (const bf16x8*)Wh;
    const bf16x8* WlF = (const bf16x8*)Wl;

#pragma unroll
    for (int kt = 0; kt < NKT; ++kt) {
        const int kof = kt * 32 + agrp * 8;
        bf16x8 a0h = *(const bf16x8*)&Fh[arow][kof];
        bf16x8 a1h = *(const bf16x8*)&Fh[16 + arow][kof];
        bf16x8 a0l = *(const bf16x8*)&Fl[arow][kof];
        bf16x8 a1l = *(const bf16x8*)&Fl[16 + arow][kof];
        bf16x8 b0h = WhF[(kt * 8 + ng0) * 64 + lane];
        bf16x8 b1h = WhF[(kt * 8 + ng0 + 1) * 64 + lane];
        bf16x8 b0l = WlF[(kt * 8 + ng0) * 64 + lane];
        bf16x8 b1l = WlF[(kt * 8 + ng0 + 1) * 64 + lane];

        acc[0][0] = __builtin_amdgcn_mfma_f32_16x16x32_bf16(a0h, b0h, acc[0][0], 0, 0, 0);
        acc[0][0] = __builtin_amdgcn_mfma_f32_16x16x32_bf16(a0h, b0l, acc[0][0], 0, 0, 0);
        acc[0][0] = __builtin_amdgcn_mfma_f32_16x16x32_bf16(a0l, b0h, acc[0][0], 0, 0, 0);
        acc[0][1] = __builtin_amdgcn_mfma_f32_16x16x32_bf16(a0h, b1h, acc[0][1], 0, 0, 0);
        acc[0][1] = __builtin_amdgcn_mfma_f32_16x16x32_bf16(a0h, b1l, acc[0][1], 0, 0, 0);
        acc[0][1] = __builtin_amdgcn_mfma_f32_16x16x32_bf16(a0l, b1h, acc[0][1], 0, 0, 0);
        acc[1][0] = __builtin_amdgcn_mfma_f32_16x16x32_bf16(a1h, b0h, acc[1][0], 0, 0, 0);
        acc[1][0] = __builtin_amdgcn_mfma_f32_16x16x32_bf16(a1h, b0l, acc[1][0], 0, 0, 0);
        acc[1][0] = __builtin_amdgcn_mfma_f32_16x16x32_bf16(a1l, b0h, acc[1][0], 0, 0, 0);
        acc[1][1] = __builtin_amdgcn_mfma_f32_16x16x32_bf16(a1h, b1h, acc[1][1], 0, 0, 0);
        acc[1][1] = __builtin_amdgcn_mfma_f32_16x16x32_bf16(a1h, b1l, acc[1][1], 0, 0, 0);
        acc[1][1] = __builtin_amdgcn_mfma_f32_16x16x32_bf16(a1l, b1h, acc[1][1], 0, 0, 0);
    }

    // scatter accumulators to Esh[row][col]
#pragma unroll
    for (int m = 0; m < 2; ++m)
#pragma unroll
        for (int n = 0; n < 2; ++n)
#pragma unroll
            for (int r = 0; r < 4; ++r)
                Esh[m * 16 + agrp * 4 + r][(ng0 + n) * 16 + arow] = acc[m][n][r];
    __syncthreads();

    // --- LayerNorm + store: wave w owns edges w*8 .. w*8+7 ---
    const float g0 = ln_g[lane], g1 = ln_g[lane + 64];
    const float bb0 = ln_b[lane], bb1 = ln_b[lane + 64];
#pragma unroll
    for (int ee = 0; ee < 8; ++ee) {
        int eg = w * 8 + ee;
        if (eg >= KNB) break;
        float v0 = Esh[eg][lane];
        float v1 = Esh[eg][lane + 64];
        float s = v0 + v1;
        float q = v0 * v0 + v1 * v1;
        for (int off = 32; off; off >>= 1) {
            s += __shfl_xor(s, off);
            q += __shfl_xor(q, off);
        }
        float mean = s * (1.f / 128.f);
        float var = q * (1.f / 128.f) - mean * mean;
        float inv = 1.f / sqrtf(var + 1e-5f);
        size_t base = ((size_t)row * KNB + eg) * NC;
        outE[base + lane]      = (v0 - mean) * inv * g0 + bb0;
        outE[base + lane + 64] = (v1 - mean) * inv * g1 + bb1;
    }
}

// ---------------------------------------------------------------------------
extern "C" void kernel_launch(void* const* d_in, const int* in_sizes, int n_in,
                              void* d_out, int out_size, void* d_ws, size_t ws_size,
                              hipStream_t stream) {
    const float* Ca     = (const float*)d_in[0];
    const float* mask   = (const float*)d_in[1];
    const int*   ridx   = (const int*)d_in[2];
    const int*   clab   = (const int*)d_in[3];
    const float* pos_W  = (const float*)d_in[4];
    const float* pos_b  = (const float*)d_in[5];
    const float* edge_W = (const float*)d_in[6];
    const float* ln_g   = (const float*)d_in[7];
    const float* ln_b   = (const float*)d_in[8];

    float* outE  = (float*)d_out;
    float* EidxF = outE + (size_t)Bc * Lc * KNB * NC;   // output 1 (as float values)

    float* Dn    = (float*)d_ws;                           // B*L*30 f32
    float* Omat  = Dn + (size_t)Bc * Lc * KNB;             // B*L*9 f32
    int*   EidxI = (int*)(Omat + (size_t)Bc * Lc * 9);     // B*L*30 i32
    unsigned short* Wh = (unsigned short*)(EidxI + (size_t)Bc * Lc * KNB);
    unsigned short* Wl = Wh + (size_t)NKT * 8 * 64 * 8;    // 24576 each

    const int rows = Bc * Lc;
    pack_kernel<<<12, 256, 0, stream>>>(edge_W, Wh, Wl);
    topk_kernel<<<rows, 256, 0, stream>>>(Ca, mask, Dn, EidxF, EidxI);
    orient_kernel<<<(rows + 255) / 256, 256, 0, stream>>>(Ca, Omat);
    edge_kernel<<<rows, 256, 0, stream>>>(Ca, ridx, clab, pos_W, pos_b, Wh, Wl,
                                          ln_g, ln_b, Dn, EidxI, Omat, outE);
}

// Round 4
// 244.427 us; speedup vs baseline: 2.2147x; 1.4661x over previous
//
#include <hip/hip_runtime.h>
#include <math.h>

// Problem constants (from setup_inputs)
constexpr int Lc   = 4096;
constexpr int Bc   = 2;
constexpr int KNB  = 30;    // TOP_K
constexpr int NF   = 167;   // 16 pos + 144 rbf + 7 orient
constexpr int NC   = 128;   // output channels
constexpr int KP   = 200;   // padded K stride (bf16 elems) -> 400B row stride
constexpr int NKT  = 6;     // K-tiles of 32 (192 >= 167)
constexpr int NBIN = 2048;  // float_bits>>20 for any finite positive float
constexpr int CAP  = 1024;  // candidate capacity (expected ~50)

typedef __attribute__((ext_vector_type(8))) short bf16x8;
typedef __attribute__((ext_vector_type(4))) float f32x4;

struct V3 { float x, y, z; };

__device__ __forceinline__ float sgnf(float v) {
    return (v > 0.f) ? 1.f : ((v < 0.f) ? -1.f : 0.f);
}
__device__ __forceinline__ unsigned long long umin64(unsigned long long a, unsigned long long b) {
    return a < b ? a : b;
}
__device__ __forceinline__ void splitbf(float v, unsigned short& h, unsigned short& l) {
    unsigned u = __float_as_uint(v);
    h = (unsigned short)(u >> 16);                       // truncated bf16 hi
    float fh = __uint_as_float((unsigned)h << 16);
    l = (unsigned short)(__float_as_uint(v - fh) >> 16); // bf16 of residual
}

// ---------------------------------------------------------------------------
// Kernel 0: pack edge_W (167x128 f32) into MFMA-fragment-ordered bf16 hi/lo.
// ---------------------------------------------------------------------------
__global__ void pack_kernel(const float* __restrict__ W,
                            unsigned short* __restrict__ Wh,
                            unsigned short* __restrict__ Wl) {
    int t = blockIdx.x * blockDim.x + threadIdx.x;   // 0 .. NKT*8*64
    if (t >= NKT * 8 * 64) return;
    int lane = t & 63, nt = (t >> 6) & 7, kt = t >> 9;
    int n = nt * 16 + (lane & 15);
    int kbase = kt * 32 + (lane >> 4) * 8;
    __align__(16) unsigned short h[8], l[8];
#pragma unroll
    for (int j = 0; j < 8; ++j) {
        int k = kbase + j;
        float v = (k < NF) ? W[(size_t)k * NC + n] : 0.f;
        splitbf(v, h[j], l[j]);
    }
    size_t o = (size_t)t * 8;
    *(bf16x8*)(Wh + o) = *(const bf16x8*)h;
    *(bf16x8*)(Wl + o) = *(const bf16x8*)l;
}

// ---------------------------------------------------------------------------
// Kernel 1 (v2): masked distance + top-30 via histogram select.
// Distances in registers (coalesced strided j), 2048-bin LDS histogram on
// float_bits>>20 (order-preserving for positive floats), wave-0 rank scan,
// candidate collect (bin <= B), single-wave exact u64-key extraction.
// ---------------------------------------------------------------------------
__global__ __launch_bounds__(256) void topk_kernel(
    const float* __restrict__ Ca, const float* __restrict__ mask,
    float* __restrict__ Dn, float* __restrict__ EidxF, int* __restrict__ EidxI) {
    const int row = blockIdx.x;                 // b*L + i
    const int b = row >> 12, i = row & (Lc - 1);
    const float* CaB = Ca + (size_t)b * Lc * 3;
    const float* mB  = mask + (size_t)b * Lc;
    const float xi = CaB[i * 3 + 0], yi = CaB[i * 3 + 1], zi = CaB[i * 3 + 2];
    const float mi = mB[i];

    __shared__ int hist[NBIN];                       // 8 KB
    __shared__ unsigned long long cand[CAP];         // 8 KB
    __shared__ float redf[4];
    __shared__ int selB;
    __shared__ int candN;

    const int t = threadIdx.x, lane = t & 63, wid = t >> 6;

    for (int q = t; q < NBIN; q += 256) hist[q] = 0;
    if (t == 0) candN = 0;

    // distances in registers, strided for coalescing
    float dm[16], m2a[16];
    float lmax = -1e30f;
#pragma unroll
    for (int k = 0; k < 16; ++k) {
        int j = t + k * 256;
        float dx = CaB[j * 3 + 0] - xi;
        float dy = CaB[j * 3 + 1] - yi;
        float dz = CaB[j * 3 + 2] - zi;
        float d = sqrtf(dx * dx + dy * dy + dz * dz + 1e-6f);
        float m2 = mi * mB[j];
        float v = m2 * d;
        dm[k] = v; m2a[k] = m2;
        lmax = fmaxf(lmax, v);
    }
    for (int off = 32; off; off >>= 1) lmax = fmaxf(lmax, __shfl_xor(lmax, off));
    if (lane == 0) redf[wid] = lmax;
    __syncthreads();
    const float dmax = fmaxf(fmaxf(redf[0], redf[1]), fmaxf(redf[2], redf[3]));

    // D_adjust + histogram
#pragma unroll
    for (int k = 0; k < 16; ++k) {
        float da = dm[k] + (1.f - m2a[k]) * dmax;
        dm[k] = da;
        int bin = min((int)(__float_as_uint(da) >> 20), NBIN - 1);
        atomicAdd(&hist[bin], 1);
    }
    __syncthreads();

    // wave 0: find bin B containing rank KNB
    if (wid == 0) {
        int s = 0;
#pragma unroll
        for (int q = 0; q < NBIN / 64; ++q) s += hist[lane * (NBIN / 64) + q];
        int sc = s;
        for (int off = 1; off < 64; off <<= 1) {
            int vv = __shfl_up(sc, off);
            if (lane >= off) sc += vv;
        }
        unsigned long long ball = __ballot(sc >= KNB);
        int gl = (int)__builtin_ctzll(ball);      // first lane reaching rank
        int before = __shfl(sc - s, gl);          // exclusive prefix there
        if (lane == gl) {
            int acc = before, Bsel = gl * (NBIN / 64) + (NBIN / 64 - 1);
            for (int q = 0; q < NBIN / 64; ++q) {
                acc += hist[gl * (NBIN / 64) + q];
                if (acc >= KNB) { Bsel = gl * (NBIN / 64) + q; break; }
            }
            selB = Bsel;
        }
    }
    __syncthreads();
    const int B = selB;

    // collect candidates (bin <= B superset of true top-30)
#pragma unroll
    for (int k = 0; k < 16; ++k) {
        unsigned bits = __float_as_uint(dm[k]);
        if ((int)min((unsigned)(bits >> 20), (unsigned)(NBIN - 1)) <= B) {
            int idx = atomicAdd(&candN, 1);
            if (idx < CAP)
                cand[idx] = ((unsigned long long)bits << 32) | (unsigned)(t + k * 256);
        }
    }
    __syncthreads();

    // wave 0: exact extraction of 30 smallest u64 keys (no barriers)
    if (wid == 0) {
        int C = candN; if (C > CAP) C = CAP;
        unsigned long long r[CAP / 64];
#pragma unroll
        for (int q = 0; q < CAP / 64; ++q) {
            int idx = lane + q * 64;
            r[q] = (idx < C) ? cand[idx] : ~0ULL;
        }
        for (int p = 0; p < KNB; ++p) {
            unsigned long long mn = r[0];
#pragma unroll
            for (int q = 1; q < CAP / 64; ++q) mn = umin64(mn, r[q]);
            for (int off = 32; off; off >>= 1) mn = umin64(mn, __shfl_xor(mn, off));
            if (lane == 0) {
                int jw = (int)(mn & 0xFFFFFFFFULL);
                EidxF[(size_t)row * KNB + p] = (float)jw;
                EidxI[(size_t)row * KNB + p] = jw;
                Dn[(size_t)row * KNB + p] = __uint_as_float((unsigned)(mn >> 32));
            }
#pragma unroll
            for (int q = 0; q < CAP / 64; ++q) if (r[q] == mn) r[q] = ~0ULL;
        }
    }
}

// ---------------------------------------------------------------------------
// Kernel 2: per-node orientation frame O (unchanged).
// ---------------------------------------------------------------------------
__device__ __forceinline__ V3 unit_seg(float dx, float dy, float dz) {
    float n = sqrtf(dx * dx + dy * dy + dz * dz);
    float m = (n > 3.6f && n < 4.0f) ? 1.f : 0.f;
    float nn = fmaxf(m * n, 1e-12f);
    V3 r; r.x = dx * m / nn; r.y = dy * m / nn; r.z = dz * m / nn;
    return r;
}

__global__ void orient_kernel(const float* __restrict__ Ca, float* __restrict__ O) {
    int idx = blockIdx.x * blockDim.x + threadIdx.x;
    if (idx >= Bc * Lc) return;
    int b = idx >> 12, l = idx & (Lc - 1);
    float* o = O + (size_t)idx * 9;
    if (l < 1 || l >= Lc - 2) {
#pragma unroll
        for (int q = 0; q < 9; ++q) o[q] = 0.f;
        return;
    }
    const float* C = Ca + ((size_t)b * Lc + (l - 1)) * 3;
    float ax = C[0], ay = C[1], az = C[2];
    float bx = C[3], by = C[4], bz = C[5];
    float cx = C[6], cy = C[7], cz = C[8];
    V3 u2 = unit_seg(bx - ax, by - ay, bz - az);
    V3 u1 = unit_seg(cx - bx, cy - by, cz - bz);
    float nx = u2.y * u1.z - u2.z * u1.y;
    float ny = u2.z * u1.x - u2.x * u1.z;
    float nz = u2.x * u1.y - u2.y * u1.x;
    float nn = fmaxf(sqrtf(nx * nx + ny * ny + nz * nz), 1e-12f);
    nx /= nn; ny /= nn; nz /= nn;
    float ox = u2.x - u1.x, oy = u2.y - u1.y, oz = u2.z - u1.z;
    float on = fmaxf(sqrtf(ox * ox + oy * oy + oz * oz), 1e-12f);
    ox /= on; oy /= on; oz /= on;
    float rx = oy * nz - oz * ny;
    float ry = oz * nx - ox * nz;
    float rz = ox * ny - oy * nx;
    o[0] = ox; o[1] = oy; o[2] = oz;
    o[3] = nx; o[4] = ny; o[5] = nz;
    o[6] = rx; o[7] = ry; o[8] = rz;
}

// ---------------------------------------------------------------------------
// Kernel 3: fused per-edge features + split-bf16 MFMA matmul + LayerNorm
// (unchanged from R3).
// ---------------------------------------------------------------------------
__global__ __launch_bounds__(256) void edge_kernel(
    const float* __restrict__ Ca, const int* __restrict__ ridx,
    const int* __restrict__ clab, const float* __restrict__ pos_W,
    const float* __restrict__ pos_b,
    const unsigned short* __restrict__ Wh, const unsigned short* __restrict__ Wl,
    const float* __restrict__ ln_g, const float* __restrict__ ln_b,
    const float* __restrict__ Dn, const int* __restrict__ EidxI,
    const float* __restrict__ Omat, float* __restrict__ outE) {
    const int row = blockIdx.x;                 // b*L + i
    const int b = row >> 12, i = row & (Lc - 1);
    const int tid = threadIdx.x, lane = tid & 63, w = tid >> 6;

    __shared__ __align__(16) unsigned short Fh[32][KP];   // 12.5 KB
    __shared__ __align__(16) unsigned short Fl[32][KP];   // 12.5 KB
    __shared__ __align__(16) float Esh[32][132];          // 16.5 KB
    __shared__ int Ej[32];

    const float* CaB = Ca + (size_t)b * Lc * 3;

    {
        unsigned* z1 = (unsigned*)&Fh[0][0];
        unsigned* z2 = (unsigned*)&Fl[0][0];
        for (int q = tid; q < 32 * KP / 2; q += 256) { z1[q] = 0u; z2[q] = 0u; }
        if (tid < KNB) Ej[tid] = EidxI[(size_t)row * KNB + tid];
    }
    __syncthreads();

    auto putF = [&](int e, int k, float v) {
        unsigned short h, l;
        splitbf(v, h, l);
        Fh[e][k] = h; Fl[e][k] = l;
    };
    auto loadC = [&](int n) {
        V3 r;
        if (n >= 0 && n < Lc) { r.x = CaB[n*3]; r.y = CaB[n*3+1]; r.z = CaB[n*3+2]; }
        else { r.x = 0.f; r.y = 0.f; r.z = 0.f; }
        return r;
    };
    const int pa_t[10] = {0,0,0,2,0,0,1,1,2,2};
    const int pb_t[10] = {0,0,0,2,1,2,0,2,0,1};

    for (int task = tid; task < 330; task += 256) {
        int e = task % 30;
        int g = task / 30;
        int j = Ej[e];
        if (g == 0) {
            int off = ridx[(size_t)b * Lc + i] - ridx[(size_t)b * Lc + j];
            int ec = (clab[(size_t)b * Lc + i] == clab[(size_t)b * Lc + j]) ? 1 : 0;
            int d = ec ? min(max(off + 32, 0), 64) : 65;
#pragma unroll
            for (int c = 0; c < 16; ++c) putF(e, c, pos_W[d * 16 + c] + pos_b[c]);
        } else if (g < 10) {
            float D;
            if (g == 1) {
                D = Dn[(size_t)row * KNB + e];
            } else {
                V3 A = loadC(i - 1 + pa_t[g]);
                V3 B = loadC(j - 1 + pb_t[g]);
                float dx = A.x - B.x, dy = A.y - B.y, dz = A.z - B.z;
                D = sqrtf(dx * dx + dy * dy + dz * dz + 1e-6f);
            }
            int k0 = 16 * g;
#pragma unroll
            for (int m = 0; m < 16; ++m) {
                float mu = 2.f + (20.f / 15.f) * (float)m;
                float z = (D - mu) * (1.f / 1.25f);
                putF(e, k0 + m, __expf(-z * z));
            }
        } else {
            const float* Om = Omat + (size_t)row * 9;
            const float* On = Omat + ((size_t)b * Lc + j) * 9;
            V3 Ai = loadC(i), Bj = loadC(j);
            float dvx = Bj.x - Ai.x, dvy = Bj.y - Ai.y, dvz = Bj.z - Ai.z;
            float u0 = Om[0] * dvx + Om[1] * dvy + Om[2] * dvz;
            float u1 = Om[3] * dvx + Om[4] * dvy + Om[5] * dvz;
            float u2 = Om[6] * dvx + Om[7] * dvy + Om[8] * dvz;
            float un = fmaxf(sqrtf(u0 * u0 + u1 * u1 + u2 * u2), 1e-12f);
            putF(e, 160, u0 / un); putF(e, 161, u1 / un); putF(e, 162, u2 / un);
            float R[3][3];
#pragma unroll
            for (int a = 0; a < 3; ++a)
#pragma unroll
                for (int m = 0; m < 3; ++m)
                    R[a][m] = Om[0 * 3 + a] * On[0 * 3 + m] +
                              Om[1 * 3 + a] * On[1 * 3 + m] +
                              Om[2 * 3 + a] * On[2 * 3 + m];
            float Rxx = R[0][0], Ryy = R[1][1], Rzz = R[2][2];
            float m0 = 0.5f * sqrtf(fabsf(1.f + Rxx - Ryy - Rzz));
            float m1 = 0.5f * sqrtf(fabsf(1.f - Rxx + Ryy - Rzz));
            float m2 = 0.5f * sqrtf(fabsf(1.f - Rxx - Ryy + Rzz));
            float qx = sgnf(R[2][1] - R[1][2]) * m0;
            float qy = sgnf(R[0][2] - R[2][0]) * m1;
            float qz = sgnf(R[1][0] - R[0][1]) * m2;
            float qw = sqrtf(fmaxf(0.f, 1.f + Rxx + Ryy + Rzz)) * 0.5f;
            float qn = fmaxf(sqrtf(qx * qx + qy * qy + qz * qz + qw * qw), 1e-12f);
            putF(e, 163, qx / qn); putF(e, 164, qy / qn);
            putF(e, 165, qz / qn); putF(e, 166, qw / qn);
        }
    }
    __syncthreads();

    const int arow = lane & 15, agrp = lane >> 4;
    const int ng0 = w * 2;
    f32x4 acc[2][2];
#pragma unroll
    for (int m = 0; m < 2; ++m)
#pragma unroll
        for (int n = 0; n < 2; ++n) acc[m][n] = (f32x4){0.f, 0.f, 0.f, 0.f};

    const bf16x8* WhF = (const bf16x8*)Wh;
    const bf16x8* WlF = (const bf16x8*)Wl;

#pragma unroll
    for (int kt = 0; kt < NKT; ++kt) {
        const int kof = kt * 32 + agrp * 8;
        bf16x8 a0h = *(const bf16x8*)&Fh[arow][kof];
        bf16x8 a1h = *(const bf16x8*)&Fh[16 + arow][kof];
        bf16x8 a0l = *(const bf16x8*)&Fl[arow][kof];
        bf16x8 a1l = *(const bf16x8*)&Fl[16 + arow][kof];
        bf16x8 b0h = WhF[(kt * 8 + ng0) * 64 + lane];
        bf16x8 b1h = WhF[(kt * 8 + ng0 + 1) * 64 + lane];
        bf16x8 b0l = WlF[(kt * 8 + ng0) * 64 + lane];
        bf16x8 b1l = WlF[(kt * 8 + ng0 + 1) * 64 + lane];

        acc[0][0] = __builtin_amdgcn_mfma_f32_16x16x32_bf16(a0h, b0h, acc[0][0], 0, 0, 0);
        acc[0][0] = __builtin_amdgcn_mfma_f32_16x16x32_bf16(a0h, b0l, acc[0][0], 0, 0, 0);
        acc[0][0] = __builtin_amdgcn_mfma_f32_16x16x32_bf16(a0l, b0h, acc[0][0], 0, 0, 0);
        acc[0][1] = __builtin_amdgcn_mfma_f32_16x16x32_bf16(a0h, b1h, acc[0][1], 0, 0, 0);
        acc[0][1] = __builtin_amdgcn_mfma_f32_16x16x32_bf16(a0h, b1l, acc[0][1], 0, 0, 0);
        acc[0][1] = __builtin_amdgcn_mfma_f32_16x16x32_bf16(a0l, b1h, acc[0][1], 0, 0, 0);
        acc[1][0] = __builtin_amdgcn_mfma_f32_16x16x32_bf16(a1h, b0h, acc[1][0], 0, 0, 0);
        acc[1][0] = __builtin_amdgcn_mfma_f32_16x16x32_bf16(a1h, b0l, acc[1][0], 0, 0, 0);
        acc[1][0] = __builtin_amdgcn_mfma_f32_16x16x32_bf16(a1l, b0h, acc[1][0], 0, 0, 0);
        acc[1][1] = __builtin_amdgcn_mfma_f32_16x16x32_bf16(a1h, b1h, acc[1][1], 0, 0, 0);
        acc[1][1] = __builtin_amdgcn_mfma_f32_16x16x32_bf16(a1h, b1l, acc[1][1], 0, 0, 0);
        acc[1][1] = __builtin_amdgcn_mfma_f32_16x16x32_bf16(a1l, b1h, acc[1][1], 0, 0, 0);
    }

#pragma unroll
    for (int m = 0; m < 2; ++m)
#pragma unroll
        for (int n = 0; n < 2; ++n)
#pragma unroll
            for (int r = 0; r < 4; ++r)
                Esh[m * 16 + agrp * 4 + r][(ng0 + n) * 16 + arow] = acc[m][n][r];
    __syncthreads();

    const float g0 = ln_g[lane], g1 = ln_g[lane + 64];
    const float bb0 = ln_b[lane], bb1 = ln_b[lane + 64];
#pragma unroll
    for (int ee = 0; ee < 8; ++ee) {
        int eg = w * 8 + ee;
        if (eg >= KNB) break;
        float v0 = Esh[eg][lane];
        float v1 = Esh[eg][lane + 64];
        float s = v0 + v1;
        float q = v0 * v0 + v1 * v1;
        for (int off = 32; off; off >>= 1) {
            s += __shfl_xor(s, off);
            q += __shfl_xor(q, off);
        }
        float mean = s * (1.f / 128.f);
        float var = q * (1.f / 128.f) - mean * mean;
        float inv = 1.f / sqrtf(var + 1e-5f);
        size_t base = ((size_t)row * KNB + eg) * NC;
        outE[base + lane]      = (v0 - mean) * inv * g0 + bb0;
        outE[base + lane + 64] = (v1 - mean) * inv * g1 + bb1;
    }
}

// ---------------------------------------------------------------------------
extern "C" void kernel_launch(void* const* d_in, const int* in_sizes, int n_in,
                              void* d_out, int out_size, void* d_ws, size_t ws_size,
                              hipStream_t stream) {
    const float* Ca     = (const float*)d_in[0];
    const float* mask   = (const float*)d_in[1];
    const int*   ridx   = (const int*)d_in[2];
    const int*   clab   = (const int*)d_in[3];
    const float* pos_W  = (const float*)d_in[4];
    const float* pos_b  = (const float*)d_in[5];
    const float* edge_W = (const float*)d_in[6];
    const float* ln_g   = (const float*)d_in[7];
    const float* ln_b   = (const float*)d_in[8];

    float* outE  = (float*)d_out;
    float* EidxF = outE + (size_t)Bc * Lc * KNB * NC;   // output 1 (as float values)

    float* Dn    = (float*)d_ws;                           // B*L*30 f32
    float* Omat  = Dn + (size_t)Bc * Lc * KNB;             // B*L*9 f32
    int*   EidxI = (int*)(Omat + (size_t)Bc * Lc * 9);     // B*L*30 i32
    unsigned short* Wh = (unsigned short*)(EidxI + (size_t)Bc * Lc * KNB);
    unsigned short* Wl = Wh + (size_t)NKT * 8 * 64 * 8;    // 24576 each

    const int rows = Bc * Lc;
    pack_kernel<<<12, 256, 0, stream>>>(edge_W, Wh, Wl);
    topk_kernel<<<rows, 256, 0, stream>>>(Ca, mask, Dn, EidxF, EidxI);
    orient_kernel<<<(rows + 255) / 256, 256, 0, stream>>>(Ca, Omat);
    edge_kernel<<<rows, 256, 0, stream>>>(Ca, ridx, clab, pos_W, pos_b, Wh, Wl,
                                          ln_g, ln_b, Dn, EidxI, Omat, outE);
}

// Round 5
// 205.415 us; speedup vs baseline: 2.6353x; 1.1899x over previous
//
#include <hip/hip_runtime.h>
#include <math.h>

// Problem constants (from setup_inputs)
constexpr int Lc   = 4096;
constexpr int Bc   = 2;
constexpr int KNB  = 30;    // TOP_K
constexpr int NF   = 167;   // 16 pos + 144 rbf + 7 orient
constexpr int NC   = 128;   // output channels
constexpr int KP   = 200;   // padded K stride (bf16 elems) -> 400B row stride
constexpr int NKT  = 6;     // K-tiles of 32 (192 >= 167)
constexpr int CAP  = 512;   // candidate capacity (threshold loop keeps c <= CAP)

typedef __attribute__((ext_vector_type(8))) short bf16x8;
typedef __attribute__((ext_vector_type(4))) float f32x4;

struct V3 { float x, y, z; };

__device__ __forceinline__ float sgnf(float v) {
    return (v > 0.f) ? 1.f : ((v < 0.f) ? -1.f : 0.f);
}
__device__ __forceinline__ unsigned long long umin64(unsigned long long a, unsigned long long b) {
    return a < b ? a : b;
}
__device__ __forceinline__ void splitbf(float v, unsigned short& h, unsigned short& l) {
    unsigned u = __float_as_uint(v);
    h = (unsigned short)(u >> 16);                       // truncated bf16 hi
    float fh = __uint_as_float((unsigned)h << 16);
    l = (unsigned short)(__float_as_uint(v - fh) >> 16); // bf16 of residual
}

// ---------------------------------------------------------------------------
// Kernel 0: pack edge_W (167x128 f32) into MFMA-fragment-ordered bf16 hi/lo.
// ---------------------------------------------------------------------------
__global__ void pack_kernel(const float* __restrict__ W,
                            unsigned short* __restrict__ Wh,
                            unsigned short* __restrict__ Wl) {
    int t = blockIdx.x * blockDim.x + threadIdx.x;   // 0 .. NKT*8*64
    if (t >= NKT * 8 * 64) return;
    int lane = t & 63, nt = (t >> 6) & 7, kt = t >> 9;
    int n = nt * 16 + (lane & 15);
    int kbase = kt * 32 + (lane >> 4) * 8;
    __align__(16) unsigned short h[8], l[8];
#pragma unroll
    for (int j = 0; j < 8; ++j) {
        int k = kbase + j;
        float v = (k < NF) ? W[(size_t)k * NC + n] : 0.f;
        splitbf(v, h[j], l[j]);
    }
    size_t o = (size_t)t * 8;
    *(bf16x8*)(Wh + o) = *(const bf16x8*)h;
    *(bf16x8*)(Wl + o) = *(const bf16x8*)l;
}

// ---------------------------------------------------------------------------
// Kernel 1 (v3): masked distance + top-30 via atomic-free threshold select.
// Distances in registers; block count(<=T) via popcount+shuffle reduce
// (no LDS atomics); T refined multiplicatively from the cubic-density
// estimate T0 = dmax*(30/4096)^(1/3); candidates (<=T, 30<=c<=CAP) extracted
// exactly by wave 0 via u64 (bits<<32|j) min-extraction (JAX tie semantics).
// ---------------------------------------------------------------------------
__global__ __launch_bounds__(256) void topk_kernel(
    const float* __restrict__ Ca, const float* __restrict__ mask,
    float* __restrict__ Dn, float* __restrict__ EidxF, int* __restrict__ EidxI) {
    const int row = blockIdx.x;                 // b*L + i
    const int b = row >> 12, i = row & (Lc - 1);
    const float* CaB = Ca + (size_t)b * Lc * 3;
    const float* mB  = mask + (size_t)b * Lc;
    const float xi = CaB[i * 3 + 0], yi = CaB[i * 3 + 1], zi = CaB[i * 3 + 2];
    const float mi = mB[i];

    __shared__ unsigned long long cand[CAP];         // 4 KB
    __shared__ float redf[4];
    __shared__ int redi[4];
    __shared__ int candN;

    const int t = threadIdx.x, lane = t & 63, wid = t >> 6;
    if (t == 0) candN = 0;

    // distances in registers, strided for coalescing
    float dm[16], m2a[16];
    float lmax = -1e30f;
#pragma unroll
    for (int k = 0; k < 16; ++k) {
        int j = t + k * 256;
        float dx = CaB[j * 3 + 0] - xi;
        float dy = CaB[j * 3 + 1] - yi;
        float dz = CaB[j * 3 + 2] - zi;
        float d = sqrtf(dx * dx + dy * dy + dz * dz + 1e-6f);
        float m2 = mi * mB[j];
        float v = m2 * d;
        dm[k] = v; m2a[k] = m2;
        lmax = fmaxf(lmax, v);
    }
    for (int off = 32; off; off >>= 1) lmax = fmaxf(lmax, __shfl_xor(lmax, off));
    if (lane == 0) redf[wid] = lmax;
    __syncthreads();
    const float dmax = fmaxf(fmaxf(redf[0], redf[1]), fmaxf(redf[2], redf[3]));

    // D_adjust (identity when mask==1, kept faithful)
#pragma unroll
    for (int k = 0; k < 16; ++k) dm[k] = dm[k] + (1.f - m2a[k]) * dmax;

    // --- threshold search: find T with KNB <= count(<=T) <= CAP ---
    float T = dmax * 0.19435f;     // (30/4096)^(1/3)
    int c, iter = 0;
    for (;;) {
        int lc = 0;
#pragma unroll
        for (int k = 0; k < 16; ++k) lc += (dm[k] <= T) ? 1 : 0;
        for (int off = 32; off; off >>= 1) lc += __shfl_xor(lc, off);
        __syncthreads();                     // protect redi reuse
        if (lane == 0) redi[wid] = lc;
        __syncthreads();
        c = redi[0] + redi[1] + redi[2] + redi[3];
        if (c >= KNB && c <= CAP) break;
        if (++iter > 20) break;              // pathological fallback (never hit here)
        if (c < KNB)
            T *= (c == 0) ? 2.0f : fminf(2.0f, 1.15f * cbrtf((float)(KNB + 10) / (float)c));
        else
            T *= 0.7f;
    }

    // collect candidates (<= T)
#pragma unroll
    for (int k = 0; k < 16; ++k) {
        if (dm[k] <= T) {
            int idx = atomicAdd(&candN, 1);
            if (idx < CAP)
                cand[idx] = ((unsigned long long)__float_as_uint(dm[k]) << 32) |
                            (unsigned)(t + k * 256);
        }
    }
    __syncthreads();

    // wave 0: exact extraction of 30 smallest u64 keys (no barriers)
    if (wid == 0) {
        int C = candN; if (C > CAP) C = CAP;
        unsigned long long r[CAP / 64];
#pragma unroll
        for (int q = 0; q < CAP / 64; ++q) {
            int idx = lane + q * 64;
            r[q] = (idx < C) ? cand[idx] : ~0ULL;
        }
        for (int p = 0; p < KNB; ++p) {
            unsigned long long mn = r[0];
#pragma unroll
            for (int q = 1; q < CAP / 64; ++q) mn = umin64(mn, r[q]);
            for (int off = 32; off; off >>= 1) mn = umin64(mn, __shfl_xor(mn, off));
            if (lane == 0) {
                int jw = (int)(mn & 0xFFFFFFFFULL);
                EidxF[(size_t)row * KNB + p] = (float)jw;
                EidxI[(size_t)row * KNB + p] = jw;
                Dn[(size_t)row * KNB + p] = __uint_as_float((unsigned)(mn >> 32));
            }
#pragma unroll
            for (int q = 0; q < CAP / 64; ++q) if (r[q] == mn) r[q] = ~0ULL;
        }
    }
}

// ---------------------------------------------------------------------------
// Kernel 2: per-node orientation frame O (unchanged).
// ---------------------------------------------------------------------------
__device__ __forceinline__ V3 unit_seg(float dx, float dy, float dz) {
    float n = sqrtf(dx * dx + dy * dy + dz * dz);
    float m = (n > 3.6f && n < 4.0f) ? 1.f : 0.f;
    float nn = fmaxf(m * n, 1e-12f);
    V3 r; r.x = dx * m / nn; r.y = dy * m / nn; r.z = dz * m / nn;
    return r;
}

__global__ void orient_kernel(const float* __restrict__ Ca, float* __restrict__ O) {
    int idx = blockIdx.x * blockDim.x + threadIdx.x;
    if (idx >= Bc * Lc) return;
    int b = idx >> 12, l = idx & (Lc - 1);
    float* o = O + (size_t)idx * 9;
    if (l < 1 || l >= Lc - 2) {
#pragma unroll
        for (int q = 0; q < 9; ++q) o[q] = 0.f;
        return;
    }
    const float* C = Ca + ((size_t)b * Lc + (l - 1)) * 3;
    float ax = C[0], ay = C[1], az = C[2];
    float bx = C[3], by = C[4], bz = C[5];
    float cx = C[6], cy = C[7], cz = C[8];
    V3 u2 = unit_seg(bx - ax, by - ay, bz - az);
    V3 u1 = unit_seg(cx - bx, cy - by, cz - bz);
    float nx = u2.y * u1.z - u2.z * u1.y;
    float ny = u2.z * u1.x - u2.x * u1.z;
    float nz = u2.x * u1.y - u2.y * u1.x;
    float nn = fmaxf(sqrtf(nx * nx + ny * ny + nz * nz), 1e-12f);
    nx /= nn; ny /= nn; nz /= nn;
    float ox = u2.x - u1.x, oy = u2.y - u1.y, oz = u2.z - u1.z;
    float on = fmaxf(sqrtf(ox * ox + oy * oy + oz * oz), 1e-12f);
    ox /= on; oy /= on; oz /= on;
    float rx = oy * nz - oz * ny;
    float ry = oz * nx - ox * nz;
    float rz = ox * ny - oy * nx;
    o[0] = ox; o[1] = oy; o[2] = oz;
    o[3] = nx; o[4] = ny; o[5] = nz;
    o[6] = rx; o[7] = ry; o[8] = rz;
}

// ---------------------------------------------------------------------------
// Kernel 3: fused per-edge features + split-bf16 MFMA matmul + LayerNorm
// (unchanged from R3).
// ---------------------------------------------------------------------------
__global__ __launch_bounds__(256) void edge_kernel(
    const float* __restrict__ Ca, const int* __restrict__ ridx,
    const int* __restrict__ clab, const float* __restrict__ pos_W,
    const float* __restrict__ pos_b,
    const unsigned short* __restrict__ Wh, const unsigned short* __restrict__ Wl,
    const float* __restrict__ ln_g, const float* __restrict__ ln_b,
    const float* __restrict__ Dn, const int* __restrict__ EidxI,
    const float* __restrict__ Omat, float* __restrict__ outE) {
    const int row = blockIdx.x;                 // b*L + i
    const int b = row >> 12, i = row & (Lc - 1);
    const int tid = threadIdx.x, lane = tid & 63, w = tid >> 6;

    __shared__ __align__(16) unsigned short Fh[32][KP];   // 12.5 KB
    __shared__ __align__(16) unsigned short Fl[32][KP];   // 12.5 KB
    __shared__ __align__(16) float Esh[32][132];          // 16.5 KB
    __shared__ int Ej[32];

    const float* CaB = Ca + (size_t)b * Lc * 3;

    {
        unsigned* z1 = (unsigned*)&Fh[0][0];
        unsigned* z2 = (unsigned*)&Fl[0][0];
        for (int q = tid; q < 32 * KP / 2; q += 256) { z1[q] = 0u; z2[q] = 0u; }
        if (tid < KNB) Ej[tid] = EidxI[(size_t)row * KNB + tid];
    }
    __syncthreads();

    auto putF = [&](int e, int k, float v) {
        unsigned short h, l;
        splitbf(v, h, l);
        Fh[e][k] = h; Fl[e][k] = l;
    };
    auto loadC = [&](int n) {
        V3 r;
        if (n >= 0 && n < Lc) { r.x = CaB[n*3]; r.y = CaB[n*3+1]; r.z = CaB[n*3+2]; }
        else { r.x = 0.f; r.y = 0.f; r.z = 0.f; }
        return r;
    };
    const int pa_t[10] = {0,0,0,2,0,0,1,1,2,2};
    const int pb_t[10] = {0,0,0,2,1,2,0,2,0,1};

    for (int task = tid; task < 330; task += 256) {
        int e = task % 30;
        int g = task / 30;
        int j = Ej[e];
        if (g == 0) {
            int off = ridx[(size_t)b * Lc + i] - ridx[(size_t)b * Lc + j];
            int ec = (clab[(size_t)b * Lc + i] == clab[(size_t)b * Lc + j]) ? 1 : 0;
            int d = ec ? min(max(off + 32, 0), 64) : 65;
#pragma unroll
            for (int c = 0; c < 16; ++c) putF(e, c, pos_W[d * 16 + c] + pos_b[c]);
        } else if (g < 10) {
            float D;
            if (g == 1) {
                D = Dn[(size_t)row * KNB + e];
            } else {
                V3 A = loadC(i - 1 + pa_t[g]);
                V3 B = loadC(j - 1 + pb_t[g]);
                float dx = A.x - B.x, dy = A.y - B.y, dz = A.z - B.z;
                D = sqrtf(dx * dx + dy * dy + dz * dz + 1e-6f);
            }
            int k0 = 16 * g;
#pragma unroll
            for (int m = 0; m < 16; ++m) {
                float mu = 2.f + (20.f / 15.f) * (float)m;
                float z = (D - mu) * (1.f / 1.25f);
                putF(e, k0 + m, __expf(-z * z));
            }
        } else {
            const float* Om = Omat + (size_t)row * 9;
            const float* On = Omat + ((size_t)b * Lc + j) * 9;
            V3 Ai = loadC(i), Bj = loadC(j);
            float dvx = Bj.x - Ai.x, dvy = Bj.y - Ai.y, dvz = Bj.z - Ai.z;
            float u0 = Om[0] * dvx + Om[1] * dvy + Om[2] * dvz;
            float u1 = Om[3] * dvx + Om[4] * dvy + Om[5] * dvz;
            float u2 = Om[6] * dvx + Om[7] * dvy + Om[8] * dvz;
            float un = fmaxf(sqrtf(u0 * u0 + u1 * u1 + u2 * u2), 1e-12f);
            putF(e, 160, u0 / un); putF(e, 161, u1 / un); putF(e, 162, u2 / un);
            float R[3][3];
#pragma unroll
            for (int a = 0; a < 3; ++a)
#pragma unroll
                for (int m = 0; m < 3; ++m)
                    R[a][m] = Om[0 * 3 + a] * On[0 * 3 + m] +
                              Om[1 * 3 + a] * On[1 * 3 + m] +
                              Om[2 * 3 + a] * On[2 * 3 + m];
            float Rxx = R[0][0], Ryy = R[1][1], Rzz = R[2][2];
            float m0 = 0.5f * sqrtf(fabsf(1.f + Rxx - Ryy - Rzz));
            float m1 = 0.5f * sqrtf(fabsf(1.f - Rxx + Ryy - Rzz));
            float m2 = 0.5f * sqrtf(fabsf(1.f - Rxx - Ryy + Rzz));
            float qx = sgnf(R[2][1] - R[1][2]) * m0;
            float qy = sgnf(R[0][2] - R[2][0]) * m1;
            float qz = sgnf(R[1][0] - R[0][1]) * m2;
            float qw = sqrtf(fmaxf(0.f, 1.f + Rxx + Ryy + Rzz)) * 0.5f;
            float qn = fmaxf(sqrtf(qx * qx + qy * qy + qz * qz + qw * qw), 1e-12f);
            putF(e, 163, qx / qn); putF(e, 164, qy / qn);
            putF(e, 165, qz / qn); putF(e, 166, qw / qn);
        }
    }
    __syncthreads();

    const int arow = lane & 15, agrp = lane >> 4;
    const int ng0 = w * 2;
    f32x4 acc[2][2];
#pragma unroll
    for (int m = 0; m < 2; ++m)
#pragma unroll
        for (int n = 0; n < 2; ++n) acc[m][n] = (f32x4){0.f, 0.f, 0.f, 0.f};

    const bf16x8* WhF = (const bf16x8*)Wh;
    const bf16x8* WlF = (const bf16x8*)Wl;

#pragma unroll
    for (int kt = 0; kt < NKT; ++kt) {
        const int kof = kt * 32 + agrp * 8;
        bf16x8 a0h = *(const bf16x8*)&Fh[arow][kof];
        bf16x8 a1h = *(const bf16x8*)&Fh[16 + arow][kof];
        bf16x8 a0l = *(const bf16x8*)&Fl[arow][kof];
        bf16x8 a1l = *(const bf16x8*)&Fl[16 + arow][kof];
        bf16x8 b0h = WhF[(kt * 8 + ng0) * 64 + lane];
        bf16x8 b1h = WhF[(kt * 8 + ng0 + 1) * 64 + lane];
        bf16x8 b0l = WlF[(kt * 8 + ng0) * 64 + lane];
        bf16x8 b1l = WlF[(kt * 8 + ng0 + 1) * 64 + lane];

        acc[0][0] = __builtin_amdgcn_mfma_f32_16x16x32_bf16(a0h, b0h, acc[0][0], 0, 0, 0);
        acc[0][0] = __builtin_amdgcn_mfma_f32_16x16x32_bf16(a0h, b0l, acc[0][0], 0, 0, 0);
        acc[0][0] = __builtin_amdgcn_mfma_f32_16x16x32_bf16(a0l, b0h, acc[0][0], 0, 0, 0);
        acc[0][1] = __builtin_amdgcn_mfma_f32_16x16x32_bf16(a0h, b1h, acc[0][1], 0, 0, 0);
        acc[0][1] = __builtin_amdgcn_mfma_f32_16x16x32_bf16(a0h, b1l, acc[0][1], 0, 0, 0);
        acc[0][1] = __builtin_amdgcn_mfma_f32_16x16x32_bf16(a0l, b1h, acc[0][1], 0, 0, 0);
        acc[1][0] = __builtin_amdgcn_mfma_f32_16x16x32_bf16(a1h, b0h, acc[1][0], 0, 0, 0);
        acc[1][0] = __builtin_amdgcn_mfma_f32_16x16x32_bf16(a1h, b0l, acc[1][0], 0, 0, 0);
        acc[1][0] = __builtin_amdgcn_mfma_f32_16x16x32_bf16(a1l, b0h, acc[1][0], 0, 0, 0);
        acc[1][1] = __builtin_amdgcn_mfma_f32_16x16x32_bf16(a1h, b1h, acc[1][1], 0, 0, 0);
        acc[1][1] = __builtin_amdgcn_mfma_f32_16x16x32_bf16(a1h, b1l, acc[1][1], 0, 0, 0);
        acc[1][1] = __builtin_amdgcn_mfma_f32_16x16x32_bf16(a1l, b1h, acc[1][1], 0, 0, 0);
    }

#pragma unroll
    for (int m = 0; m < 2; ++m)
#pragma unroll
        for (int n = 0; n < 2; ++n)
#pragma unroll
            for (int r = 0; r < 4; ++r)
                Esh[m * 16 + agrp * 4 + r][(ng0 + n) * 16 + arow] = acc[m][n][r];
    __syncthreads();

    const float g0 = ln_g[lane], g1 = ln_g[lane + 64];
    const float bb0 = ln_b[lane], bb1 = ln_b[lane + 64];
#pragma unroll
    for (int ee = 0; ee < 8; ++ee) {
        int eg = w * 8 + ee;
        if (eg >= KNB) break;
        float v0 = Esh[eg][lane];
        float v1 = Esh[eg][lane + 64];
        float s = v0 + v1;
        float q = v0 * v0 + v1 * v1;
        for (int off = 32; off; off >>= 1) {
            s += __shfl_xor(s, off);
            q += __shfl_xor(q, off);
        }
        float mean = s * (1.f / 128.f);
        float var = q * (1.f / 128.f) - mean * mean;
        float inv = 1.f / sqrtf(var + 1e-5f);
        size_t base = ((size_t)row * KNB + eg) * NC;
        outE[base + lane]      = (v0 - mean) * inv * g0 + bb0;
        outE[base + lane + 64] = (v1 - mean) * inv * g1 + bb1;
    }
}

// ---------------------------------------------------------------------------
extern "C" void kernel_launch(void* const* d_in, const int* in_sizes, int n_in,
                              void* d_out, int out_size, void* d_ws, size_t ws_size,
                              hipStream_t stream) {
    const float* Ca     = (const float*)d_in[0];
    const float* mask   = (const float*)d_in[1];
    const int*   ridx   = (const int*)d_in[2];
    const int*   clab   = (const int*)d_in[3];
    const float* pos_W  = (const float*)d_in[4];
    const float* pos_b  = (const float*)d_in[5];
    const float* edge_W = (const float*)d_in[6];
    const float* ln_g   = (const float*)d_in[7];
    const float* ln_b   = (const float*)d_in[8];

    float* outE  = (float*)d_out;
    float* EidxF = outE + (size_t)Bc * Lc * KNB * NC;   // output 1 (as float values)

    float* Dn    = (float*)d_ws;                           // B*L*30 f32
    float* Omat  = Dn + (size_t)Bc * Lc * KNB;             // B*L*9 f32
    int*   EidxI = (int*)(Omat + (size_t)Bc * Lc * 9);     // B*L*30 i32
    unsigned short* Wh = (unsigned short*)(EidxI + (size_t)Bc * Lc * KNB);
    unsigned short* Wl = Wh + (size_t)NKT * 8 * 64 * 8;    // 24576 each

    const int rows = Bc * Lc;
    pack_kernel<<<12, 256, 0, stream>>>(edge_W, Wh, Wl);
    topk_kernel<<<rows, 256, 0, stream>>>(Ca, mask, Dn, EidxF, EidxI);
    orient_kernel<<<(rows + 255) / 256, 256, 0, stream>>>(Ca, Omat);
    edge_kernel<<<rows, 256, 0, stream>>>(Ca, ridx, clab, pos_W, pos_b, Wh, Wl,
                                          ln_g, ln_b, Dn, EidxI, Omat, outE);
}

// Round 6
// 174.551 us; speedup vs baseline: 3.1013x; 1.1768x over previous
//
#include <hip/hip_runtime.h>
#include <math.h>

// Problem constants (from setup_inputs)
constexpr int Lc   = 4096;
constexpr int Bc   = 2;
constexpr int KNB  = 30;    // TOP_K
constexpr int NF   = 167;   // 16 pos + 144 rbf + 7 orient
constexpr int NC   = 128;   // output channels
constexpr int KP   = 200;   // padded K stride (bf16 elems) -> 400B row stride (2-way bank = free)
constexpr int NKT  = 6;     // K-tiles of 32 (192 >= 167)
constexpr int CAP  = 512;   // candidate capacity (threshold loop keeps c <= CAP)

typedef __attribute__((ext_vector_type(8))) short bf16x8;
typedef __attribute__((ext_vector_type(4))) float f32x4;

struct V3 { float x, y, z; };

__device__ __forceinline__ float sgnf(float v) {
    return (v > 0.f) ? 1.f : ((v < 0.f) ? -1.f : 0.f);
}
__device__ __forceinline__ unsigned long long umin64(unsigned long long a, unsigned long long b) {
    return a < b ? a : b;
}
__device__ __forceinline__ void splitbf(float v, unsigned short& h, unsigned short& l) {
    unsigned u = __float_as_uint(v);
    h = (unsigned short)(u >> 16);                       // truncated bf16 hi
    float fh = __uint_as_float((unsigned)h << 16);
    l = (unsigned short)(__float_as_uint(v - fh) >> 16); // bf16 of residual
}

// ---------------------------------------------------------------------------
// Kernel 0: pack edge_W (167x128 f32) into MFMA-fragment-ordered bf16 hi/lo.
// ---------------------------------------------------------------------------
__global__ void pack_kernel(const float* __restrict__ W,
                            unsigned short* __restrict__ Wh,
                            unsigned short* __restrict__ Wl) {
    int t = blockIdx.x * blockDim.x + threadIdx.x;   // 0 .. NKT*8*64
    if (t >= NKT * 8 * 64) return;
    int lane = t & 63, nt = (t >> 6) & 7, kt = t >> 9;
    int n = nt * 16 + (lane & 15);
    int kbase = kt * 32 + (lane >> 4) * 8;
    __align__(16) unsigned short h[8], l[8];
#pragma unroll
    for (int j = 0; j < 8; ++j) {
        int k = kbase + j;
        float v = (k < NF) ? W[(size_t)k * NC + n] : 0.f;
        splitbf(v, h[j], l[j]);
    }
    size_t o = (size_t)t * 8;
    *(bf16x8*)(Wh + o) = *(const bf16x8*)h;
    *(bf16x8*)(Wl + o) = *(const bf16x8*)l;
}

// ---------------------------------------------------------------------------
// Kernel 1 (v3): masked distance + top-30 via atomic-free threshold select
// (unchanged from R5).
// ---------------------------------------------------------------------------
__global__ __launch_bounds__(256) void topk_kernel(
    const float* __restrict__ Ca, const float* __restrict__ mask,
    float* __restrict__ Dn, float* __restrict__ EidxF, int* __restrict__ EidxI) {
    const int row = blockIdx.x;                 // b*L + i
    const int b = row >> 12, i = row & (Lc - 1);
    const float* CaB = Ca + (size_t)b * Lc * 3;
    const float* mB  = mask + (size_t)b * Lc;
    const float xi = CaB[i * 3 + 0], yi = CaB[i * 3 + 1], zi = CaB[i * 3 + 2];
    const float mi = mB[i];

    __shared__ unsigned long long cand[CAP];         // 4 KB
    __shared__ float redf[4];
    __shared__ int redi[4];
    __shared__ int candN;

    const int t = threadIdx.x, lane = t & 63, wid = t >> 6;
    if (t == 0) candN = 0;

    float dm[16], m2a[16];
    float lmax = -1e30f;
#pragma unroll
    for (int k = 0; k < 16; ++k) {
        int j = t + k * 256;
        float dx = CaB[j * 3 + 0] - xi;
        float dy = CaB[j * 3 + 1] - yi;
        float dz = CaB[j * 3 + 2] - zi;
        float d = sqrtf(dx * dx + dy * dy + dz * dz + 1e-6f);
        float m2 = mi * mB[j];
        float v = m2 * d;
        dm[k] = v; m2a[k] = m2;
        lmax = fmaxf(lmax, v);
    }
    for (int off = 32; off; off >>= 1) lmax = fmaxf(lmax, __shfl_xor(lmax, off));
    if (lane == 0) redf[wid] = lmax;
    __syncthreads();
    const float dmax = fmaxf(fmaxf(redf[0], redf[1]), fmaxf(redf[2], redf[3]));

#pragma unroll
    for (int k = 0; k < 16; ++k) dm[k] = dm[k] + (1.f - m2a[k]) * dmax;

    float T = dmax * 0.19435f;     // (30/4096)^(1/3)
    int c, iter = 0;
    for (;;) {
        int lc = 0;
#pragma unroll
        for (int k = 0; k < 16; ++k) lc += (dm[k] <= T) ? 1 : 0;
        for (int off = 32; off; off >>= 1) lc += __shfl_xor(lc, off);
        __syncthreads();
        if (lane == 0) redi[wid] = lc;
        __syncthreads();
        c = redi[0] + redi[1] + redi[2] + redi[3];
        if (c >= KNB && c <= CAP) break;
        if (++iter > 20) break;
        if (c < KNB)
            T *= (c == 0) ? 2.0f : fminf(2.0f, 1.15f * cbrtf((float)(KNB + 10) / (float)c));
        else
            T *= 0.7f;
    }

#pragma unroll
    for (int k = 0; k < 16; ++k) {
        if (dm[k] <= T) {
            int idx = atomicAdd(&candN, 1);
            if (idx < CAP)
                cand[idx] = ((unsigned long long)__float_as_uint(dm[k]) << 32) |
                            (unsigned)(t + k * 256);
        }
    }
    __syncthreads();

    if (wid == 0) {
        int C = candN; if (C > CAP) C = CAP;
        unsigned long long r[CAP / 64];
#pragma unroll
        for (int q = 0; q < CAP / 64; ++q) {
            int idx = lane + q * 64;
            r[q] = (idx < C) ? cand[idx] : ~0ULL;
        }
        for (int p = 0; p < KNB; ++p) {
            unsigned long long mn = r[0];
#pragma unroll
            for (int q = 1; q < CAP / 64; ++q) mn = umin64(mn, r[q]);
            for (int off = 32; off; off >>= 1) mn = umin64(mn, __shfl_xor(mn, off));
            if (lane == 0) {
                int jw = (int)(mn & 0xFFFFFFFFULL);
                EidxF[(size_t)row * KNB + p] = (float)jw;
                EidxI[(size_t)row * KNB + p] = jw;
                Dn[(size_t)row * KNB + p] = __uint_as_float((unsigned)(mn >> 32));
            }
#pragma unroll
            for (int q = 0; q < CAP / 64; ++q) if (r[q] == mn) r[q] = ~0ULL;
        }
    }
}

// ---------------------------------------------------------------------------
// Kernel 2: per-node orientation frame O (unchanged).
// ---------------------------------------------------------------------------
__device__ __forceinline__ V3 unit_seg(float dx, float dy, float dz) {
    float n = sqrtf(dx * dx + dy * dy + dz * dz);
    float m = (n > 3.6f && n < 4.0f) ? 1.f : 0.f;
    float nn = fmaxf(m * n, 1e-12f);
    V3 r; r.x = dx * m / nn; r.y = dy * m / nn; r.z = dz * m / nn;
    return r;
}

__global__ void orient_kernel(const float* __restrict__ Ca, float* __restrict__ O) {
    int idx = blockIdx.x * blockDim.x + threadIdx.x;
    if (idx >= Bc * Lc) return;
    int b = idx >> 12, l = idx & (Lc - 1);
    float* o = O + (size_t)idx * 9;
    if (l < 1 || l >= Lc - 2) {
#pragma unroll
        for (int q = 0; q < 9; ++q) o[q] = 0.f;
        return;
    }
    const float* C = Ca + ((size_t)b * Lc + (l - 1)) * 3;
    float ax = C[0], ay = C[1], az = C[2];
    float bx = C[3], by = C[4], bz = C[5];
    float cx = C[6], cy = C[7], cz = C[8];
    V3 u2 = unit_seg(bx - ax, by - ay, bz - az);
    V3 u1 = unit_seg(cx - bx, cy - by, cz - bz);
    float nx = u2.y * u1.z - u2.z * u1.y;
    float ny = u2.z * u1.x - u2.x * u1.z;
    float nz = u2.x * u1.y - u2.y * u1.x;
    float nn = fmaxf(sqrtf(nx * nx + ny * ny + nz * nz), 1e-12f);
    nx /= nn; ny /= nn; nz /= nn;
    float ox = u2.x - u1.x, oy = u2.y - u1.y, oz = u2.z - u1.z;
    float on = fmaxf(sqrtf(ox * ox + oy * oy + oz * oz), 1e-12f);
    ox /= on; oy /= on; oz /= on;
    float rx = oy * nz - oz * ny;
    float ry = oz * nx - ox * nz;
    float rz = ox * ny - oy * nx;
    o[0] = ox; o[1] = oy; o[2] = oz;
    o[3] = nx; o[4] = ny; o[5] = nz;
    o[6] = rx; o[7] = ry; o[8] = rz;
}

// ---------------------------------------------------------------------------
// Kernel 3 (v2): fused features + split-bf16 MFMA + in-register LayerNorm.
// LN stats from accumulators (4-level shuffle over arow), direct global
// store — no Esh round-trip. LDS ~27 KB -> ~6 blocks/CU.
// ---------------------------------------------------------------------------
__global__ __launch_bounds__(256) void edge_kernel(
    const float* __restrict__ Ca, const int* __restrict__ ridx,
    const int* __restrict__ clab, const float* __restrict__ pos_W,
    const float* __restrict__ pos_b,
    const unsigned short* __restrict__ Wh, const unsigned short* __restrict__ Wl,
    const float* __restrict__ ln_g, const float* __restrict__ ln_b,
    const float* __restrict__ Dn, const int* __restrict__ EidxI,
    const float* __restrict__ Omat, float* __restrict__ outE) {
    const int row = blockIdx.x;                 // b*L + i
    const int b = row >> 12, i = row & (Lc - 1);
    const int tid = threadIdx.x, lane = tid & 63, w = tid >> 6;

    __shared__ __align__(16) unsigned short Fh[32][KP];   // 12.5 KB
    __shared__ __align__(16) unsigned short Fl[32][KP];   // 12.5 KB
    __shared__ float Ssum[32][4];
    __shared__ float Ssq[32][4];
    __shared__ float2 Mstat[32];                          // (mean, inv)
    __shared__ int Ej[32];

    const float* CaB = Ca + (size_t)b * Lc * 3;

    // --- targeted zero-fill: only padding (cols 167..199 all rows; rows 30,31) ---
    for (int q = tid; q < 32 * 33; q += 256) {
        int r = q / 33, c = 167 + q % 33;
        Fh[r][c] = 0; Fl[r][c] = 0;
    }
    for (int q = tid; q < 2 * 167; q += 256) {
        int r = 30 + q / 167, c = q % 167;
        Fh[r][c] = 0; Fl[r][c] = 0;
    }
    if (tid < KNB) Ej[tid] = EidxI[(size_t)row * KNB + tid];
    __syncthreads();

    // --- feature build: 330 tasks of ~16 features over 256 threads ---
    auto putF = [&](int e, int k, float v) {
        unsigned short h, l;
        splitbf(v, h, l);
        Fh[e][k] = h; Fl[e][k] = l;
    };
    auto loadC = [&](int n) {
        V3 r;
        if (n >= 0 && n < Lc) { r.x = CaB[n*3]; r.y = CaB[n*3+1]; r.z = CaB[n*3+2]; }
        else { r.x = 0.f; r.y = 0.f; r.z = 0.f; }
        return r;
    };
    const int pa_t[10] = {0,0,0,2,0,0,1,1,2,2};
    const int pb_t[10] = {0,0,0,2,1,2,0,2,0,1};

    for (int task = tid; task < 330; task += 256) {
        int e = task % 30;
        int g = task / 30;
        int j = Ej[e];
        if (g == 0) {
            int off = ridx[(size_t)b * Lc + i] - ridx[(size_t)b * Lc + j];
            int ec = (clab[(size_t)b * Lc + i] == clab[(size_t)b * Lc + j]) ? 1 : 0;
            int d = ec ? min(max(off + 32, 0), 64) : 65;
#pragma unroll
            for (int c = 0; c < 16; ++c) putF(e, c, pos_W[d * 16 + c] + pos_b[c]);
        } else if (g < 10) {
            float D;
            if (g == 1) {
                D = Dn[(size_t)row * KNB + e];
            } else {
                V3 A = loadC(i - 1 + pa_t[g]);
                V3 B = loadC(j - 1 + pb_t[g]);
                float dx = A.x - B.x, dy = A.y - B.y, dz = A.z - B.z;
                D = sqrtf(dx * dx + dy * dy + dz * dz + 1e-6f);
            }
            int k0 = 16 * g;
#pragma unroll
            for (int m = 0; m < 16; ++m) {
                float mu = 2.f + (20.f / 15.f) * (float)m;
                float z = (D - mu) * (1.f / 1.25f);
                putF(e, k0 + m, __expf(-z * z));
            }
        } else {
            const float* Om = Omat + (size_t)row * 9;
            const float* On = Omat + ((size_t)b * Lc + j) * 9;
            V3 Ai = loadC(i), Bj = loadC(j);
            float dvx = Bj.x - Ai.x, dvy = Bj.y - Ai.y, dvz = Bj.z - Ai.z;
            float u0 = Om[0] * dvx + Om[1] * dvy + Om[2] * dvz;
            float u1 = Om[3] * dvx + Om[4] * dvy + Om[5] * dvz;
            float u2 = Om[6] * dvx + Om[7] * dvy + Om[8] * dvz;
            float un = fmaxf(sqrtf(u0 * u0 + u1 * u1 + u2 * u2), 1e-12f);
            putF(e, 160, u0 / un); putF(e, 161, u1 / un); putF(e, 162, u2 / un);
            float R[3][3];
#pragma unroll
            for (int a = 0; a < 3; ++a)
#pragma unroll
                for (int m = 0; m < 3; ++m)
                    R[a][m] = Om[0 * 3 + a] * On[0 * 3 + m] +
                              Om[1 * 3 + a] * On[1 * 3 + m] +
                              Om[2 * 3 + a] * On[2 * 3 + m];
            float Rxx = R[0][0], Ryy = R[1][1], Rzz = R[2][2];
            float m0 = 0.5f * sqrtf(fabsf(1.f + Rxx - Ryy - Rzz));
            float m1 = 0.5f * sqrtf(fabsf(1.f - Rxx + Ryy - Rzz));
            float m2 = 0.5f * sqrtf(fabsf(1.f - Rxx - Ryy + Rzz));
            float qx = sgnf(R[2][1] - R[1][2]) * m0;
            float qy = sgnf(R[0][2] - R[2][0]) * m1;
            float qz = sgnf(R[1][0] - R[0][1]) * m2;
            float qw = sqrtf(fmaxf(0.f, 1.f + Rxx + Ryy + Rzz)) * 0.5f;
            float qn = fmaxf(sqrtf(qx * qx + qy * qy + qz * qz + qw * qw), 1e-12f);
            putF(e, 163, qx / qn); putF(e, 164, qy / qn);
            putF(e, 165, qz / qn); putF(e, 166, qw / qn);
        }
    }
    __syncthreads();

    // --- MFMA phase: wave w owns N columns [w*32, w*32+32) ---
    const int arow = lane & 15, agrp = lane >> 4;
    const int ng0 = w * 2;
    f32x4 acc[2][2];
#pragma unroll
    for (int m = 0; m < 2; ++m)
#pragma unroll
        for (int n = 0; n < 2; ++n) acc[m][n] = (f32x4){0.f, 0.f, 0.f, 0.f};

    const bf16x8* WhF = (const bf16x8*)Wh;
    const bf16x8* WlF = (const bf16x8*)Wl;

#pragma unroll
    for (int kt = 0; kt < NKT; ++kt) {
        const int kof = kt * 32 + agrp * 8;
        bf16x8 a0h = *(const bf16x8*)&Fh[arow][kof];
        bf16x8 a1h = *(const bf16x8*)&Fh[16 + arow][kof];
        bf16x8 a0l = *(const bf16x8*)&Fl[arow][kof];
        bf16x8 a1l = *(const bf16x8*)&Fl[16 + arow][kof];
        bf16x8 b0h = WhF[(kt * 8 + ng0) * 64 + lane];
        bf16x8 b1h = WhF[(kt * 8 + ng0 + 1) * 64 + lane];
        bf16x8 b0l = WlF[(kt * 8 + ng0) * 64 + lane];
        bf16x8 b1l = WlF[(kt * 8 + ng0 + 1) * 64 + lane];

        acc[0][0] = __builtin_amdgcn_mfma_f32_16x16x32_bf16(a0h, b0h, acc[0][0], 0, 0, 0);
        acc[0][0] = __builtin_amdgcn_mfma_f32_16x16x32_bf16(a0h, b0l, acc[0][0], 0, 0, 0);
        acc[0][0] = __builtin_amdgcn_mfma_f32_16x16x32_bf16(a0l, b0h, acc[0][0], 0, 0, 0);
        acc[0][1] = __builtin_amdgcn_mfma_f32_16x16x32_bf16(a0h, b1h, acc[0][1], 0, 0, 0);
        acc[0][1] = __builtin_amdgcn_mfma_f32_16x16x32_bf16(a0h, b1l, acc[0][1], 0, 0, 0);
        acc[0][1] = __builtin_amdgcn_mfma_f32_16x16x32_bf16(a0l, b1h, acc[0][1], 0, 0, 0);
        acc[1][0] = __builtin_amdgcn_mfma_f32_16x16x32_bf16(a1h, b0h, acc[1][0], 0, 0, 0);
        acc[1][0] = __builtin_amdgcn_mfma_f32_16x16x32_bf16(a1h, b0l, acc[1][0], 0, 0, 0);
        acc[1][0] = __builtin_amdgcn_mfma_f32_16x16x32_bf16(a1l, b0h, acc[1][0], 0, 0, 0);
        acc[1][1] = __builtin_amdgcn_mfma_f32_16x16x32_bf16(a1h, b1h, acc[1][1], 0, 0, 0);
        acc[1][1] = __builtin_amdgcn_mfma_f32_16x16x32_bf16(a1h, b1l, acc[1][1], 0, 0, 0);
        acc[1][1] = __builtin_amdgcn_mfma_f32_16x16x32_bf16(a1l, b1h, acc[1][1], 0, 0, 0);
    }

    // --- LN stats from accumulators: per-wave partials + 4-level arow reduce ---
    float ps[2][4], pq[2][4];
#pragma unroll
    for (int m = 0; m < 2; ++m)
#pragma unroll
        for (int r = 0; r < 4; ++r) {
            float v0 = acc[m][0][r], v1 = acc[m][1][r];
            ps[m][r] = v0 + v1;
            pq[m][r] = v0 * v0 + v1 * v1;
        }
#pragma unroll
    for (int off = 1; off < 16; off <<= 1) {
#pragma unroll
        for (int m = 0; m < 2; ++m)
#pragma unroll
            for (int r = 0; r < 4; ++r) {
                ps[m][r] += __shfl_xor(ps[m][r], off);
                pq[m][r] += __shfl_xor(pq[m][r], off);
            }
    }
    if (arow == 0) {
#pragma unroll
        for (int m = 0; m < 2; ++m)
#pragma unroll
            for (int r = 0; r < 4; ++r) {
                int me = m * 16 + agrp * 4 + r;
                Ssum[me][w] = ps[m][r];
                Ssq[me][w] = pq[m][r];
            }
    }
    __syncthreads();
    if (tid < 32) {
        float s = Ssum[tid][0] + Ssum[tid][1] + Ssum[tid][2] + Ssum[tid][3];
        float q = Ssq[tid][0] + Ssq[tid][1] + Ssq[tid][2] + Ssq[tid][3];
        float mean = s * (1.f / 128.f);
        float var = q * (1.f / 128.f) - mean * mean;
        Mstat[tid] = make_float2(mean, 1.f / sqrtf(var + 1e-5f));
    }
    __syncthreads();

    // --- normalize in-register + direct global store ---
    float gg[2], bb[2];
#pragma unroll
    for (int n = 0; n < 2; ++n) {
        int ce = (ng0 + n) * 16 + arow;
        gg[n] = ln_g[ce];
        bb[n] = ln_b[ce];
    }
#pragma unroll
    for (int m = 0; m < 2; ++m)
#pragma unroll
        for (int r = 0; r < 4; ++r) {
            int me = m * 16 + agrp * 4 + r;
            if (me >= KNB) continue;
            float2 st = Mstat[me];
            size_t base = ((size_t)row * KNB + me) * NC;
#pragma unroll
            for (int n = 0; n < 2; ++n) {
                int ce = (ng0 + n) * 16 + arow;
                outE[base + ce] = (acc[m][n][r] - st.x) * st.y * gg[n] + bb[n];
            }
        }
}

// ---------------------------------------------------------------------------
extern "C" void kernel_launch(void* const* d_in, const int* in_sizes, int n_in,
                              void* d_out, int out_size, void* d_ws, size_t ws_size,
                              hipStream_t stream) {
    const float* Ca     = (const float*)d_in[0];
    const float* mask   = (const float*)d_in[1];
    const int*   ridx   = (const int*)d_in[2];
    const int*   clab   = (const int*)d_in[3];
    const float* pos_W  = (const float*)d_in[4];
    const float* pos_b  = (const float*)d_in[5];
    const float* edge_W = (const float*)d_in[6];
    const float* ln_g   = (const float*)d_in[7];
    const float* ln_b   = (const float*)d_in[8];

    float* outE  = (float*)d_out;
    float* EidxF = outE + (size_t)Bc * Lc * KNB * NC;   // output 1 (as float values)

    float* Dn    = (float*)d_ws;                           // B*L*30 f32
    float* Omat  = Dn + (size_t)Bc * Lc * KNB;             // B*L*9 f32
    int*   EidxI = (int*)(Omat + (size_t)Bc * Lc * 9);     // B*L*30 i32
    unsigned short* Wh = (unsigned short*)(EidxI + (size_t)Bc * Lc * KNB);
    unsigned short* Wl = Wh + (size_t)NKT * 8 * 64 * 8;    // 24576 each

    const int rows = Bc * Lc;
    pack_kernel<<<12, 256, 0, stream>>>(edge_W, Wh, Wl);
    topk_kernel<<<rows, 256, 0, stream>>>(Ca, mask, Dn, EidxF, EidxI);
    orient_kernel<<<(rows + 255) / 256, 256, 0, stream>>>(Ca, Omat);
    edge_kernel<<<rows, 256, 0, stream>>>(Ca, ridx, clab, pos_W, pos_b, Wh, Wl,
                                          ln_g, ln_b, Dn, EidxI, Omat, outE);
}

// Round 7
// 144.413 us; speedup vs baseline: 3.7485x; 1.2087x over previous
//
#include <hip/hip_runtime.h>
#include <math.h>

// Problem constants (from setup_inputs)
constexpr int Lc   = 4096;
constexpr int Bc   = 2;
constexpr int KNB  = 30;    // TOP_K
constexpr int NF   = 167;   // 16 pos + 144 rbf + 7 orient
constexpr int NC   = 128;   // output channels
constexpr int KP   = 200;   // padded K stride (bf16 elems) -> 400B row stride (2-way bank = free)
constexpr int NKT  = 6;     // K-tiles of 32 (192 >= 167)
constexpr int CAP  = 512;   // fallback candidate capacity

typedef __attribute__((ext_vector_type(8))) short bf16x8;
typedef __attribute__((ext_vector_type(4))) float f32x4;

struct V3 { float x, y, z; };

__device__ __forceinline__ float sgnf(float v) {
    return (v > 0.f) ? 1.f : ((v < 0.f) ? -1.f : 0.f);
}
__device__ __forceinline__ unsigned long long umin64(unsigned long long a, unsigned long long b) {
    return a < b ? a : b;
}
__device__ __forceinline__ void splitbf(float v, unsigned short& h, unsigned short& l) {
    unsigned u = __float_as_uint(v);
    h = (unsigned short)(u >> 16);                       // truncated bf16 hi
    float fh = __uint_as_float((unsigned)h << 16);
    l = (unsigned short)(__float_as_uint(v - fh) >> 16); // bf16 of residual
}

// ---------------------------------------------------------------------------
// Kernel 0: pack edge_W (167x128 f32) into MFMA-fragment-ordered bf16 hi/lo.
// ---------------------------------------------------------------------------
__global__ void pack_kernel(const float* __restrict__ W,
                            unsigned short* __restrict__ Wh,
                            unsigned short* __restrict__ Wl) {
    int t = blockIdx.x * blockDim.x + threadIdx.x;   // 0 .. NKT*8*64
    if (t >= NKT * 8 * 64) return;
    int lane = t & 63, nt = (t >> 6) & 7, kt = t >> 9;
    int n = nt * 16 + (lane & 15);
    int kbase = kt * 32 + (lane >> 4) * 8;
    __align__(16) unsigned short h[8], l[8];
#pragma unroll
    for (int j = 0; j < 8; ++j) {
        int k = kbase + j;
        float v = (k < NF) ? W[(size_t)k * NC + n] : 0.f;
        splitbf(v, h[j], l[j]);
    }
    size_t o = (size_t)t * 8;
    *(bf16x8*)(Wh + o) = *(const bf16x8*)h;
    *(bf16x8*)(Wl + o) = *(const bf16x8*)l;
}

// ---------------------------------------------------------------------------
// Kernel 1 (v4): masked distance + top-30.
// Threshold refined to get 30 <= c <= 64 candidates (atomic-free popcount
// counting, 1 barrier/iter); exact sorted top-30 via 64-lane bitonic sort of
// (float_bits<<32 | j) keys — exact JAX top_k tie semantics. Fallback
// multi-pass extraction if c in (64, 512].
// ---------------------------------------------------------------------------
__global__ __launch_bounds__(256) void topk_kernel(
    const float* __restrict__ Ca, const float* __restrict__ mask,
    float* __restrict__ Dn, float* __restrict__ EidxF, int* __restrict__ EidxI) {
    const int row = blockIdx.x;                 // b*L + i
    const int b = row >> 12, i = row & (Lc - 1);
    const float* CaB = Ca + (size_t)b * Lc * 3;
    const float* mB  = mask + (size_t)b * Lc;
    const float xi = CaB[i * 3 + 0], yi = CaB[i * 3 + 1], zi = CaB[i * 3 + 2];
    const float mi = mB[i];

    __shared__ unsigned long long cand[CAP];         // 4 KB
    __shared__ float redf[4];
    __shared__ int redi[2][4];
    __shared__ int candN;

    const int t = threadIdx.x, lane = t & 63, wid = t >> 6;
    if (t == 0) candN = 0;

    // distances in registers, strided for coalescing
    float dm[16], m2a[16];
    float lmax = -1e30f;
#pragma unroll
    for (int k = 0; k < 16; ++k) {
        int j = t + k * 256;
        float dx = CaB[j * 3 + 0] - xi;
        float dy = CaB[j * 3 + 1] - yi;
        float dz = CaB[j * 3 + 2] - zi;
        float d = sqrtf(dx * dx + dy * dy + dz * dz + 1e-6f);
        float m2 = mi * mB[j];
        float v = m2 * d;
        dm[k] = v; m2a[k] = m2;
        lmax = fmaxf(lmax, v);
    }
    for (int off = 32; off; off >>= 1) lmax = fmaxf(lmax, __shfl_xor(lmax, off));
    if (lane == 0) redf[wid] = lmax;
    __syncthreads();
    const float dmax = fmaxf(fmaxf(redf[0], redf[1]), fmaxf(redf[2], redf[3]));

    // D_adjust (identity when mask==1, kept faithful)
#pragma unroll
    for (int k = 0; k < 16; ++k) dm[k] = dm[k] + (1.f - m2a[k]) * dmax;

    // --- threshold search: prefer c in [KNB, 64]; accept [KNB, CAP] late ---
    float T = dmax * 0.19435f;     // (30/4096)^(1/3)
    int c = 0;
    for (int iter = 0; iter < 32; ++iter) {
        int lc = 0;
#pragma unroll
        for (int k = 0; k < 16; ++k) lc += (dm[k] <= T) ? 1 : 0;
        for (int off = 32; off; off >>= 1) lc += __shfl_xor(lc, off);
        if (lane == 0) redi[iter & 1][wid] = lc;
        __syncthreads();
        c = redi[iter & 1][0] + redi[iter & 1][1] + redi[iter & 1][2] + redi[iter & 1][3];
        if (c >= KNB && c <= 64) break;
        if (iter >= 12 && c >= KNB && c <= CAP) break;   // fallback acceptance
        if (c < KNB)
            T *= (c == 0) ? 1.7f
                          : fminf(1.7f, 1.05f * cbrtf((float)(KNB + 15) / (float)c));
        else
            T *= fmaxf(0.55f, 1.05f * cbrtf(45.f / (float)c));
    }

    // collect candidates (<= T)
#pragma unroll
    for (int k = 0; k < 16; ++k) {
        if (dm[k] <= T) {
            int idx = atomicAdd(&candN, 1);
            if (idx < CAP)
                cand[idx] = ((unsigned long long)__float_as_uint(dm[k]) << 32) |
                            (unsigned)(t + k * 256);
        }
    }
    __syncthreads();

    if (wid == 0) {
        int C = candN; if (C > CAP) C = CAP;
        if (C <= 64) {
            // --- fast path: 64-lane bitonic sort, ascending u64 ---
            unsigned long long key = (lane < C) ? cand[lane] : ~0ULL;
#pragma unroll
            for (int size = 2; size <= 64; size <<= 1) {
#pragma unroll
                for (int stride = size >> 1; stride; stride >>= 1) {
                    unsigned long long other = __shfl_xor(key, stride);
                    bool dirUp = ((lane & size) == 0);
                    bool takeMin = ((lane & stride) == 0) ? dirUp : !dirUp;
                    bool less = other < key;
                    unsigned long long mn = less ? other : key;
                    unsigned long long mx = less ? key : other;
                    key = takeMin ? mn : mx;
                }
            }
            if (lane < KNB) {
                int jw = (int)(key & 0xFFFFFFFFULL);
                EidxF[(size_t)row * KNB + lane] = (float)jw;
                EidxI[(size_t)row * KNB + lane] = jw;
                Dn[(size_t)row * KNB + lane] = __uint_as_float((unsigned)(key >> 32));
            }
        } else {
            // --- slow path: 30-pass exact min-extraction over <=512 ---
            unsigned long long r[CAP / 64];
#pragma unroll
            for (int q = 0; q < CAP / 64; ++q) {
                int idx = lane + q * 64;
                r[q] = (idx < C) ? cand[idx] : ~0ULL;
            }
            for (int p = 0; p < KNB; ++p) {
                unsigned long long mn = r[0];
#pragma unroll
                for (int q = 1; q < CAP / 64; ++q) mn = umin64(mn, r[q]);
                for (int off = 32; off; off >>= 1) mn = umin64(mn, __shfl_xor(mn, off));
                if (lane == 0) {
                    int jw = (int)(mn & 0xFFFFFFFFULL);
                    EidxF[(size_t)row * KNB + p] = (float)jw;
                    EidxI[(size_t)row * KNB + p] = jw;
                    Dn[(size_t)row * KNB + p] = __uint_as_float((unsigned)(mn >> 32));
                }
#pragma unroll
                for (int q = 0; q < CAP / 64; ++q) if (r[q] == mn) r[q] = ~0ULL;
            }
        }
    }
}

// ---------------------------------------------------------------------------
// Kernel 2: per-node orientation frame O (unchanged).
// ---------------------------------------------------------------------------
__device__ __forceinline__ V3 unit_seg(float dx, float dy, float dz) {
    float n = sqrtf(dx * dx + dy * dy + dz * dz);
    float m = (n > 3.6f && n < 4.0f) ? 1.f : 0.f;
    float nn = fmaxf(m * n, 1e-12f);
    V3 r; r.x = dx * m / nn; r.y = dy * m / nn; r.z = dz * m / nn;
    return r;
}

__global__ void orient_kernel(const float* __restrict__ Ca, float* __restrict__ O) {
    int idx = blockIdx.x * blockDim.x + threadIdx.x;
    if (idx >= Bc * Lc) return;
    int b = idx >> 12, l = idx & (Lc - 1);
    float* o = O + (size_t)idx * 9;
    if (l < 1 || l >= Lc - 2) {
#pragma unroll
        for (int q = 0; q < 9; ++q) o[q] = 0.f;
        return;
    }
    const float* C = Ca + ((size_t)b * Lc + (l - 1)) * 3;
    float ax = C[0], ay = C[1], az = C[2];
    float bx = C[3], by = C[4], bz = C[5];
    float cx = C[6], cy = C[7], cz = C[8];
    V3 u2 = unit_seg(bx - ax, by - ay, bz - az);
    V3 u1 = unit_seg(cx - bx, cy - by, cz - bz);
    float nx = u2.y * u1.z - u2.z * u1.y;
    float ny = u2.z * u1.x - u2.x * u1.z;
    float nz = u2.x * u1.y - u2.y * u1.x;
    float nn = fmaxf(sqrtf(nx * nx + ny * ny + nz * nz), 1e-12f);
    nx /= nn; ny /= nn; nz /= nn;
    float ox = u2.x - u1.x, oy = u2.y - u1.y, oz = u2.z - u1.z;
    float on = fmaxf(sqrtf(ox * ox + oy * oy + oz * oz), 1e-12f);
    ox /= on; oy /= on; oz /= on;
    float rx = oy * nz - oz * ny;
    float ry = oz * nx - ox * nz;
    float rz = ox * ny - oy * nx;
    o[0] = ox; o[1] = oy; o[2] = oz;
    o[3] = nx; o[4] = ny; o[5] = nz;
    o[6] = rx; o[7] = ry; o[8] = rz;
}

// ---------------------------------------------------------------------------
// Kernel 3 (v2): fused features + split-bf16 MFMA + in-register LayerNorm
// (unchanged from R6).
// ---------------------------------------------------------------------------
__global__ __launch_bounds__(256) void edge_kernel(
    const float* __restrict__ Ca, const int* __restrict__ ridx,
    const int* __restrict__ clab, const float* __restrict__ pos_W,
    const float* __restrict__ pos_b,
    const unsigned short* __restrict__ Wh, const unsigned short* __restrict__ Wl,
    const float* __restrict__ ln_g, const float* __restrict__ ln_b,
    const float* __restrict__ Dn, const int* __restrict__ EidxI,
    const float* __restrict__ Omat, float* __restrict__ outE) {
    const int row = blockIdx.x;                 // b*L + i
    const int b = row >> 12, i = row & (Lc - 1);
    const int tid = threadIdx.x, lane = tid & 63, w = tid >> 6;

    __shared__ __align__(16) unsigned short Fh[32][KP];   // 12.5 KB
    __shared__ __align__(16) unsigned short Fl[32][KP];   // 12.5 KB
    __shared__ float Ssum[32][4];
    __shared__ float Ssq[32][4];
    __shared__ float2 Mstat[32];                          // (mean, inv)
    __shared__ int Ej[32];

    const float* CaB = Ca + (size_t)b * Lc * 3;

    // --- targeted zero-fill: only padding (cols 167..199 all rows; rows 30,31) ---
    for (int q = tid; q < 32 * 33; q += 256) {
        int r = q / 33, c = 167 + q % 33;
        Fh[r][c] = 0; Fl[r][c] = 0;
    }
    for (int q = tid; q < 2 * 167; q += 256) {
        int r = 30 + q / 167, c = q % 167;
        Fh[r][c] = 0; Fl[r][c] = 0;
    }
    if (tid < KNB) Ej[tid] = EidxI[(size_t)row * KNB + tid];
    __syncthreads();

    // --- feature build: 330 tasks of ~16 features over 256 threads ---
    auto putF = [&](int e, int k, float v) {
        unsigned short h, l;
        splitbf(v, h, l);
        Fh[e][k] = h; Fl[e][k] = l;
    };
    auto loadC = [&](int n) {
        V3 r;
        if (n >= 0 && n < Lc) { r.x = CaB[n*3]; r.y = CaB[n*3+1]; r.z = CaB[n*3+2]; }
        else { r.x = 0.f; r.y = 0.f; r.z = 0.f; }
        return r;
    };
    const int pa_t[10] = {0,0,0,2,0,0,1,1,2,2};
    const int pb_t[10] = {0,0,0,2,1,2,0,2,0,1};

    for (int task = tid; task < 330; task += 256) {
        int e = task % 30;
        int g = task / 30;
        int j = Ej[e];
        if (g == 0) {
            int off = ridx[(size_t)b * Lc + i] - ridx[(size_t)b * Lc + j];
            int ec = (clab[(size_t)b * Lc + i] == clab[(size_t)b * Lc + j]) ? 1 : 0;
            int d = ec ? min(max(off + 32, 0), 64) : 65;
#pragma unroll
            for (int c = 0; c < 16; ++c) putF(e, c, pos_W[d * 16 + c] + pos_b[c]);
        } else if (g < 10) {
            float D;
            if (g == 1) {
                D = Dn[(size_t)row * KNB + e];
            } else {
                V3 A = loadC(i - 1 + pa_t[g]);
                V3 B = loadC(j - 1 + pb_t[g]);
                float dx = A.x - B.x, dy = A.y - B.y, dz = A.z - B.z;
                D = sqrtf(dx * dx + dy * dy + dz * dz + 1e-6f);
            }
            int k0 = 16 * g;
#pragma unroll
            for (int m = 0; m < 16; ++m) {
                float mu = 2.f + (20.f / 15.f) * (float)m;
                float z = (D - mu) * (1.f / 1.25f);
                putF(e, k0 + m, __expf(-z * z));
            }
        } else {
            const float* Om = Omat + (size_t)row * 9;
            const float* On = Omat + ((size_t)b * Lc + j) * 9;
            V3 Ai = loadC(i), Bj = loadC(j);
            float dvx = Bj.x - Ai.x, dvy = Bj.y - Ai.y, dvz = Bj.z - Ai.z;
            float u0 = Om[0] * dvx + Om[1] * dvy + Om[2] * dvz;
            float u1 = Om[3] * dvx + Om[4] * dvy + Om[5] * dvz;
            float u2 = Om[6] * dvx + Om[7] * dvy + Om[8] * dvz;
            float un = fmaxf(sqrtf(u0 * u0 + u1 * u1 + u2 * u2), 1e-12f);
            putF(e, 160, u0 / un); putF(e, 161, u1 / un); putF(e, 162, u2 / un);
            float R[3][3];
#pragma unroll
            for (int a = 0; a < 3; ++a)
#pragma unroll
                for (int m = 0; m < 3; ++m)
                    R[a][m] = Om[0 * 3 + a] * On[0 * 3 + m] +
                              Om[1 * 3 + a] * On[1 * 3 + m] +
                              Om[2 * 3 + a] * On[2 * 3 + m];
            float Rxx = R[0][0], Ryy = R[1][1], Rzz = R[2][2];
            float m0 = 0.5f * sqrtf(fabsf(1.f + Rxx - Ryy - Rzz));
            float m1 = 0.5f * sqrtf(fabsf(1.f - Rxx + Ryy - Rzz));
            float m2 = 0.5f * sqrtf(fabsf(1.f - Rxx - Ryy + Rzz));
            float qx = sgnf(R[2][1] - R[1][2]) * m0;
            float qy = sgnf(R[0][2] - R[2][0]) * m1;
            float qz = sgnf(R[1][0] - R[0][1]) * m2;
            float qw = sqrtf(fmaxf(0.f, 1.f + Rxx + Ryy + Rzz)) * 0.5f;
            float qn = fmaxf(sqrtf(qx * qx + qy * qy + qz * qz + qw * qw), 1e-12f);
            putF(e, 163, qx / qn); putF(e, 164, qy / qn);
            putF(e, 165, qz / qn); putF(e, 166, qw / qn);
        }
    }
    __syncthreads();

    // --- MFMA phase: wave w owns N columns [w*32, w*32+32) ---
    const int arow = lane & 15, agrp = lane >> 4;
    const int ng0 = w * 2;
    f32x4 acc[2][2];
#pragma unroll
    for (int m = 0; m < 2; ++m)
#pragma unroll
        for (int n = 0; n < 2; ++n) acc[m][n] = (f32x4){0.f, 0.f, 0.f, 0.f};

    const bf16x8* WhF = (const bf16x8*)Wh;
    const bf16x8* WlF = (const bf16x8*)Wl;

#pragma unroll
    for (int kt = 0; kt < NKT; ++kt) {
        const int kof = kt * 32 + agrp * 8;
        bf16x8 a0h = *(const bf16x8*)&Fh[arow][kof];
        bf16x8 a1h = *(const bf16x8*)&Fh[16 + arow][kof];
        bf16x8 a0l = *(const bf16x8*)&Fl[arow][kof];
        bf16x8 a1l = *(const bf16x8*)&Fl[16 + arow][kof];
        bf16x8 b0h = WhF[(kt * 8 + ng0) * 64 + lane];
        bf16x8 b1h = WhF[(kt * 8 + ng0 + 1) * 64 + lane];
        bf16x8 b0l = WlF[(kt * 8 + ng0) * 64 + lane];
        bf16x8 b1l = WlF[(kt * 8 + ng0 + 1) * 64 + lane];

        acc[0][0] = __builtin_amdgcn_mfma_f32_16x16x32_bf16(a0h, b0h, acc[0][0], 0, 0, 0);
        acc[0][0] = __builtin_amdgcn_mfma_f32_16x16x32_bf16(a0h, b0l, acc[0][0], 0, 0, 0);
        acc[0][0] = __builtin_amdgcn_mfma_f32_16x16x32_bf16(a0l, b0h, acc[0][0], 0, 0, 0);
        acc[0][1] = __builtin_amdgcn_mfma_f32_16x16x32_bf16(a0h, b1h, acc[0][1], 0, 0, 0);
        acc[0][1] = __builtin_amdgcn_mfma_f32_16x16x32_bf16(a0h, b1l, acc[0][1], 0, 0, 0);
        acc[0][1] = __builtin_amdgcn_mfma_f32_16x16x32_bf16(a0l, b1h, acc[0][1], 0, 0, 0);
        acc[1][0] = __builtin_amdgcn_mfma_f32_16x16x32_bf16(a1h, b0h, acc[1][0], 0, 0, 0);
        acc[1][0] = __builtin_amdgcn_mfma_f32_16x16x32_bf16(a1h, b0l, acc[1][0], 0, 0, 0);
        acc[1][0] = __builtin_amdgcn_mfma_f32_16x16x32_bf16(a1l, b0h, acc[1][0], 0, 0, 0);
        acc[1][1] = __builtin_amdgcn_mfma_f32_16x16x32_bf16(a1h, b1h, acc[1][1], 0, 0, 0);
        acc[1][1] = __builtin_amdgcn_mfma_f32_16x16x32_bf16(a1h, b1l, acc[1][1], 0, 0, 0);
        acc[1][1] = __builtin_amdgcn_mfma_f32_16x16x32_bf16(a1l, b1h, acc[1][1], 0, 0, 0);
    }

    // --- LN stats from accumulators: per-wave partials + 4-level arow reduce ---
    float ps[2][4], pq[2][4];
#pragma unroll
    for (int m = 0; m < 2; ++m)
#pragma unroll
        for (int r = 0; r < 4; ++r) {
            float v0 = acc[m][0][r], v1 = acc[m][1][r];
            ps[m][r] = v0 + v1;
            pq[m][r] = v0 * v0 + v1 * v1;
        }
#pragma unroll
    for (int off = 1; off < 16; off <<= 1) {
#pragma unroll
        for (int m = 0; m < 2; ++m)
#pragma unroll
            for (int r = 0; r < 4; ++r) {
                ps[m][r] += __shfl_xor(ps[m][r], off);
                pq[m][r] += __shfl_xor(pq[m][r], off);
            }
    }
    if (arow == 0) {
#pragma unroll
        for (int m = 0; m < 2; ++m)
#pragma unroll
            for (int r = 0; r < 4; ++r) {
                int me = m * 16 + agrp * 4 + r;
                Ssum[me][w] = ps[m][r];
                Ssq[me][w] = pq[m][r];
            }
    }
    __syncthreads();
    if (tid < 32) {
        float s = Ssum[tid][0] + Ssum[tid][1] + Ssum[tid][2] + Ssum[tid][3];
        float q = Ssq[tid][0] + Ssq[tid][1] + Ssq[tid][2] + Ssq[tid][3];
        float mean = s * (1.f / 128.f);
        float var = q * (1.f / 128.f) - mean * mean;
        Mstat[tid] = make_float2(mean, 1.f / sqrtf(var + 1e-5f));
    }
    __syncthreads();

    // --- normalize in-register + direct global store ---
    float gg[2], bb[2];
#pragma unroll
    for (int n = 0; n < 2; ++n) {
        int ce = (ng0 + n) * 16 + arow;
        gg[n] = ln_g[ce];
        bb[n] = ln_b[ce];
    }
#pragma unroll
    for (int m = 0; m < 2; ++m)
#pragma unroll
        for (int r = 0; r < 4; ++r) {
            int me = m * 16 + agrp * 4 + r;
            if (me >= KNB) continue;
            float2 st = Mstat[me];
            size_t base = ((size_t)row * KNB + me) * NC;
#pragma unroll
            for (int n = 0; n < 2; ++n) {
                int ce = (ng0 + n) * 16 + arow;
                outE[base + ce] = (acc[m][n][r] - st.x) * st.y * gg[n] + bb[n];
            }
        }
}

// ---------------------------------------------------------------------------
extern "C" void kernel_launch(void* const* d_in, const int* in_sizes, int n_in,
                              void* d_out, int out_size, void* d_ws, size_t ws_size,
                              hipStream_t stream) {
    const float* Ca     = (const float*)d_in[0];
    const float* mask   = (const float*)d_in[1];
    const int*   ridx   = (const int*)d_in[2];
    const int*   clab   = (const int*)d_in[3];
    const float* pos_W  = (const float*)d_in[4];
    const float* pos_b  = (const float*)d_in[5];
    const float* edge_W = (const float*)d_in[6];
    const float* ln_g   = (const float*)d_in[7];
    const float* ln_b   = (const float*)d_in[8];

    float* outE  = (float*)d_out;
    float* EidxF = outE + (size_t)Bc * Lc * KNB * NC;   // output 1 (as float values)

    float* Dn    = (float*)d_ws;                           // B*L*30 f32
    float* Omat  = Dn + (size_t)Bc * Lc * KNB;             // B*L*9 f32
    int*   EidxI = (int*)(Omat + (size_t)Bc * Lc * 9);     // B*L*30 i32
    unsigned short* Wh = (unsigned short*)(EidxI + (size_t)Bc * Lc * KNB);
    unsigned short* Wl = Wh + (size_t)NKT * 8 * 64 * 8;    // 24576 each

    const int rows = Bc * Lc;
    pack_kernel<<<12, 256, 0, stream>>>(edge_W, Wh, Wl);
    topk_kernel<<<rows, 256, 0, stream>>>(Ca, mask, Dn, EidxF, EidxI);
    orient_kernel<<<(rows + 255) / 256, 256, 0, stream>>>(Ca, Omat);
    edge_kernel<<<rows, 256, 0, stream>>>(Ca, ridx, clab, pos_W, pos_b, Wh, Wl,
                                          ln_g, ln_b, Dn, EidxI, Omat, outE);
}

// Round 8
// 133.423 us; speedup vs baseline: 4.0573x; 1.0824x over previous
//
#include <hip/hip_runtime.h>
#include <math.h>

// Problem constants (from setup_inputs)
constexpr int Lc   = 4096;
constexpr int Bc   = 2;
constexpr int KNB  = 30;    // TOP_K
constexpr int NF   = 167;   // 16 pos + 144 rbf + 7 orient
constexpr int NC   = 128;   // output channels
constexpr int KP   = 200;   // padded K stride (bf16 elems) -> 400B row stride
constexpr int NKT  = 6;     // K-tiles of 32 (192 >= 167)
constexpr int CAP  = 512;   // fallback candidate capacity

typedef __attribute__((ext_vector_type(8))) short bf16x8;
typedef __attribute__((ext_vector_type(4))) float f32x4;

struct V3 { float x, y, z; };

__device__ __forceinline__ float sgnf(float v) {
    return (v > 0.f) ? 1.f : ((v < 0.f) ? -1.f : 0.f);
}
__device__ __forceinline__ unsigned long long umin64(unsigned long long a, unsigned long long b) {
    return a < b ? a : b;
}
__device__ __forceinline__ void splitbf(float v, unsigned short& h, unsigned short& l) {
    unsigned u = __float_as_uint(v);
    h = (unsigned short)(u >> 16);                       // truncated bf16 hi
    float fh = __uint_as_float((unsigned)h << 16);
    l = (unsigned short)(__float_as_uint(v - fh) >> 16); // bf16 of residual
}
__device__ __forceinline__ unsigned short bf16rne(float v) {
    unsigned u = __float_as_uint(v);
    return (unsigned short)((u + 0x7FFFu + ((u >> 16) & 1u)) >> 16);
}

// ---------------------------------------------------------------------------
// Kernel 0: pack edge_W (167x128 f32) into MFMA-fragment-ordered bf16 hi/lo.
// (W split kept: a_bf16*(Wh+Wl) == a_bf16*W exactly in f32-accum MFMA.)
// ---------------------------------------------------------------------------
__global__ void pack_kernel(const float* __restrict__ W,
                            unsigned short* __restrict__ Wh,
                            unsigned short* __restrict__ Wl) {
    int t = blockIdx.x * blockDim.x + threadIdx.x;   // 0 .. NKT*8*64
    if (t >= NKT * 8 * 64) return;
    int lane = t & 63, nt = (t >> 6) & 7, kt = t >> 9;
    int n = nt * 16 + (lane & 15);
    int kbase = kt * 32 + (lane >> 4) * 8;
    __align__(16) unsigned short h[8], l[8];
#pragma unroll
    for (int j = 0; j < 8; ++j) {
        int k = kbase + j;
        float v = (k < NF) ? W[(size_t)k * NC + n] : 0.f;
        splitbf(v, h[j], l[j]);
    }
    size_t o = (size_t)t * 8;
    *(bf16x8*)(Wh + o) = *(const bf16x8*)h;
    *(bf16x8*)(Wl + o) = *(const bf16x8*)l;
}

// ---------------------------------------------------------------------------
// Kernel 1 (v4): masked distance + top-30 (unchanged from R7).
// ---------------------------------------------------------------------------
__global__ __launch_bounds__(256) void topk_kernel(
    const float* __restrict__ Ca, const float* __restrict__ mask,
    float* __restrict__ Dn, float* __restrict__ EidxF, int* __restrict__ EidxI) {
    const int row = blockIdx.x;                 // b*L + i
    const int b = row >> 12, i = row & (Lc - 1);
    const float* CaB = Ca + (size_t)b * Lc * 3;
    const float* mB  = mask + (size_t)b * Lc;
    const float xi = CaB[i * 3 + 0], yi = CaB[i * 3 + 1], zi = CaB[i * 3 + 2];
    const float mi = mB[i];

    __shared__ unsigned long long cand[CAP];         // 4 KB
    __shared__ float redf[4];
    __shared__ int redi[2][4];
    __shared__ int candN;

    const int t = threadIdx.x, lane = t & 63, wid = t >> 6;
    if (t == 0) candN = 0;

    float dm[16], m2a[16];
    float lmax = -1e30f;
#pragma unroll
    for (int k = 0; k < 16; ++k) {
        int j = t + k * 256;
        float dx = CaB[j * 3 + 0] - xi;
        float dy = CaB[j * 3 + 1] - yi;
        float dz = CaB[j * 3 + 2] - zi;
        float d = sqrtf(dx * dx + dy * dy + dz * dz + 1e-6f);
        float m2 = mi * mB[j];
        float v = m2 * d;
        dm[k] = v; m2a[k] = m2;
        lmax = fmaxf(lmax, v);
    }
    for (int off = 32; off; off >>= 1) lmax = fmaxf(lmax, __shfl_xor(lmax, off));
    if (lane == 0) redf[wid] = lmax;
    __syncthreads();
    const float dmax = fmaxf(fmaxf(redf[0], redf[1]), fmaxf(redf[2], redf[3]));

#pragma unroll
    for (int k = 0; k < 16; ++k) dm[k] = dm[k] + (1.f - m2a[k]) * dmax;

    float T = dmax * 0.19435f;     // (30/4096)^(1/3)
    int c = 0;
    for (int iter = 0; iter < 32; ++iter) {
        int lc = 0;
#pragma unroll
        for (int k = 0; k < 16; ++k) lc += (dm[k] <= T) ? 1 : 0;
        for (int off = 32; off; off >>= 1) lc += __shfl_xor(lc, off);
        if (lane == 0) redi[iter & 1][wid] = lc;
        __syncthreads();
        c = redi[iter & 1][0] + redi[iter & 1][1] + redi[iter & 1][2] + redi[iter & 1][3];
        if (c >= KNB && c <= 64) break;
        if (iter >= 12 && c >= KNB && c <= CAP) break;   // fallback acceptance
        if (c < KNB)
            T *= (c == 0) ? 1.7f
                          : fminf(1.7f, 1.05f * cbrtf((float)(KNB + 15) / (float)c));
        else
            T *= fmaxf(0.55f, 1.05f * cbrtf(45.f / (float)c));
    }

#pragma unroll
    for (int k = 0; k < 16; ++k) {
        if (dm[k] <= T) {
            int idx = atomicAdd(&candN, 1);
            if (idx < CAP)
                cand[idx] = ((unsigned long long)__float_as_uint(dm[k]) << 32) |
                            (unsigned)(t + k * 256);
        }
    }
    __syncthreads();

    if (wid == 0) {
        int C = candN; if (C > CAP) C = CAP;
        if (C <= 64) {
            unsigned long long key = (lane < C) ? cand[lane] : ~0ULL;
#pragma unroll
            for (int size = 2; size <= 64; size <<= 1) {
#pragma unroll
                for (int stride = size >> 1; stride; stride >>= 1) {
                    unsigned long long other = __shfl_xor(key, stride);
                    bool dirUp = ((lane & size) == 0);
                    bool takeMin = ((lane & stride) == 0) ? dirUp : !dirUp;
                    bool less = other < key;
                    unsigned long long mn = less ? other : key;
                    unsigned long long mx = less ? key : other;
                    key = takeMin ? mn : mx;
                }
            }
            if (lane < KNB) {
                int jw = (int)(key & 0xFFFFFFFFULL);
                EidxF[(size_t)row * KNB + lane] = (float)jw;
                EidxI[(size_t)row * KNB + lane] = jw;
                Dn[(size_t)row * KNB + lane] = __uint_as_float((unsigned)(key >> 32));
            }
        } else {
            unsigned long long r[CAP / 64];
#pragma unroll
            for (int q = 0; q < CAP / 64; ++q) {
                int idx = lane + q * 64;
                r[q] = (idx < C) ? cand[idx] : ~0ULL;
            }
            for (int p = 0; p < KNB; ++p) {
                unsigned long long mn = r[0];
#pragma unroll
                for (int q = 1; q < CAP / 64; ++q) mn = umin64(mn, r[q]);
                for (int off = 32; off; off >>= 1) mn = umin64(mn, __shfl_xor(mn, off));
                if (lane == 0) {
                    int jw = (int)(mn & 0xFFFFFFFFULL);
                    EidxF[(size_t)row * KNB + p] = (float)jw;
                    EidxI[(size_t)row * KNB + p] = jw;
                    Dn[(size_t)row * KNB + p] = __uint_as_float((unsigned)(mn >> 32));
                }
#pragma unroll
                for (int q = 0; q < CAP / 64; ++q) if (r[q] == mn) r[q] = ~0ULL;
            }
        }
    }
}

// ---------------------------------------------------------------------------
// Kernel 2: per-node orientation frame O (unchanged).
// ---------------------------------------------------------------------------
__device__ __forceinline__ V3 unit_seg(float dx, float dy, float dz) {
    float n = sqrtf(dx * dx + dy * dy + dz * dz);
    float m = (n > 3.6f && n < 4.0f) ? 1.f : 0.f;
    float nn = fmaxf(m * n, 1e-12f);
    V3 r; r.x = dx * m / nn; r.y = dy * m / nn; r.z = dz * m / nn;
    return r;
}

__global__ void orient_kernel(const float* __restrict__ Ca, float* __restrict__ O) {
    int idx = blockIdx.x * blockDim.x + threadIdx.x;
    if (idx >= Bc * Lc) return;
    int b = idx >> 12, l = idx & (Lc - 1);
    float* o = O + (size_t)idx * 9;
    if (l < 1 || l >= Lc - 2) {
#pragma unroll
        for (int q = 0; q < 9; ++q) o[q] = 0.f;
        return;
    }
    const float* C = Ca + ((size_t)b * Lc + (l - 1)) * 3;
    float ax = C[0], ay = C[1], az = C[2];
    float bx = C[3], by = C[4], bz = C[5];
    float cx = C[6], cy = C[7], cz = C[8];
    V3 u2 = unit_seg(bx - ax, by - ay, bz - az);
    V3 u1 = unit_seg(cx - bx, cy - by, cz - bz);
    float nx = u2.y * u1.z - u2.z * u1.y;
    float ny = u2.z * u1.x - u2.x * u1.z;
    float nz = u2.x * u1.y - u2.y * u1.x;
    float nn = fmaxf(sqrtf(nx * nx + ny * ny + nz * nz), 1e-12f);
    nx /= nn; ny /= nn; nz /= nn;
    float ox = u2.x - u1.x, oy = u2.y - u1.y, oz = u2.z - u1.z;
    float on = fmaxf(sqrtf(ox * ox + oy * oy + oz * oz), 1e-12f);
    ox /= on; oy /= on; oz /= on;
    float rx = oy * nz - oz * ny;
    float ry = oz * nx - ox * nz;
    float rz = ox * ny - oy * nx;
    o[0] = ox; o[1] = oy; o[2] = oz;
    o[3] = nx; o[4] = ny; o[5] = nz;
    o[6] = rx; o[7] = ry; o[8] = rz;
}

// ---------------------------------------------------------------------------
// Kernel 3 (v3): fused features (single RNE bf16 in LDS) + MFMA
// (a * (Wh + Wl), 8 MFMA/kt) + in-register LayerNorm. LDS ~14 KB.
// ---------------------------------------------------------------------------
__global__ __launch_bounds__(256) void edge_kernel(
    const float* __restrict__ Ca, const int* __restrict__ ridx,
    const int* __restrict__ clab, const float* __restrict__ pos_W,
    const float* __restrict__ pos_b,
    const unsigned short* __restrict__ Wh, const unsigned short* __restrict__ Wl,
    const float* __restrict__ ln_g, const float* __restrict__ ln_b,
    const float* __restrict__ Dn, const int* __restrict__ EidxI,
    const float* __restrict__ Omat, float* __restrict__ outE) {
    const int row = blockIdx.x;                 // b*L + i
    const int b = row >> 12, i = row & (Lc - 1);
    const int tid = threadIdx.x, lane = tid & 63, w = tid >> 6;

    __shared__ __align__(16) unsigned short Fh[32][KP];   // 12.5 KB
    __shared__ float Ssum[32][4];
    __shared__ float Ssq[32][4];
    __shared__ float2 Mstat[32];                          // (mean, inv)
    __shared__ int Ej[32];

    const float* CaB = Ca + (size_t)b * Lc * 3;

    // --- targeted zero-fill: padding cols 167..199 all rows; rows 30,31 ---
    for (int q = tid; q < 32 * 33; q += 256) {
        int r = q / 33, c = 167 + q % 33;
        Fh[r][c] = 0;
    }
    for (int q = tid; q < 2 * 167; q += 256) {
        int r = 30 + q / 167, c = q % 167;
        Fh[r][c] = 0;
    }
    if (tid < KNB) Ej[tid] = EidxI[(size_t)row * KNB + tid];
    __syncthreads();

    // --- feature build: 330 tasks of ~16 features over 256 threads ---
    auto putF = [&](int e, int k, float v) { Fh[e][k] = bf16rne(v); };
    auto loadC = [&](int n) {
        V3 r;
        if (n >= 0 && n < Lc) { r.x = CaB[n*3]; r.y = CaB[n*3+1]; r.z = CaB[n*3+2]; }
        else { r.x = 0.f; r.y = 0.f; r.z = 0.f; }
        return r;
    };
    const int pa_t[10] = {0,0,0,2,0,0,1,1,2,2};
    const int pb_t[10] = {0,0,0,2,1,2,0,2,0,1};

    for (int task = tid; task < 330; task += 256) {
        int e = task % 30;
        int g = task / 30;
        int j = Ej[e];
        if (g == 0) {
            int off = ridx[(size_t)b * Lc + i] - ridx[(size_t)b * Lc + j];
            int ec = (clab[(size_t)b * Lc + i] == clab[(size_t)b * Lc + j]) ? 1 : 0;
            int d = ec ? min(max(off + 32, 0), 64) : 65;
#pragma unroll
            for (int c = 0; c < 16; ++c) putF(e, c, pos_W[d * 16 + c] + pos_b[c]);
        } else if (g < 10) {
            float D;
            if (g == 1) {
                D = Dn[(size_t)row * KNB + e];
            } else {
                V3 A = loadC(i - 1 + pa_t[g]);
                V3 B = loadC(j - 1 + pb_t[g]);
                float dx = A.x - B.x, dy = A.y - B.y, dz = A.z - B.z;
                D = sqrtf(dx * dx + dy * dy + dz * dz + 1e-6f);
            }
            int k0 = 16 * g;
#pragma unroll
            for (int m = 0; m < 16; ++m) {
                float mu = 2.f + (20.f / 15.f) * (float)m;
                float z = (D - mu) * (1.f / 1.25f);
                putF(e, k0 + m, __expf(-z * z));
            }
        } else {
            const float* Om = Omat + (size_t)row * 9;
            const float* On = Omat + ((size_t)b * Lc + j) * 9;
            V3 Ai = loadC(i), Bj = loadC(j);
            float dvx = Bj.x - Ai.x, dvy = Bj.y - Ai.y, dvz = Bj.z - Ai.z;
            float u0 = Om[0] * dvx + Om[1] * dvy + Om[2] * dvz;
            float u1 = Om[3] * dvx + Om[4] * dvy + Om[5] * dvz;
            float u2 = Om[6] * dvx + Om[7] * dvy + Om[8] * dvz;
            float un = fmaxf(sqrtf(u0 * u0 + u1 * u1 + u2 * u2), 1e-12f);
            putF(e, 160, u0 / un); putF(e, 161, u1 / un); putF(e, 162, u2 / un);
            float R[3][3];
#pragma unroll
            for (int a = 0; a < 3; ++a)
#pragma unroll
                for (int m = 0; m < 3; ++m)
                    R[a][m] = Om[0 * 3 + a] * On[0 * 3 + m] +
                              Om[1 * 3 + a] * On[1 * 3 + m] +
                              Om[2 * 3 + a] * On[2 * 3 + m];
            float Rxx = R[0][0], Ryy = R[1][1], Rzz = R[2][2];
            float m0 = 0.5f * sqrtf(fabsf(1.f + Rxx - Ryy - Rzz));
            float m1 = 0.5f * sqrtf(fabsf(1.f - Rxx + Ryy - Rzz));
            float m2 = 0.5f * sqrtf(fabsf(1.f - Rxx - Ryy + Rzz));
            float qx = sgnf(R[2][1] - R[1][2]) * m0;
            float qy = sgnf(R[0][2] - R[2][0]) * m1;
            float qz = sgnf(R[1][0] - R[0][1]) * m2;
            float qw = sqrtf(fmaxf(0.f, 1.f + Rxx + Ryy + Rzz)) * 0.5f;
            float qn = fmaxf(sqrtf(qx * qx + qy * qy + qz * qz + qw * qw), 1e-12f);
            putF(e, 163, qx / qn); putF(e, 164, qy / qn);
            putF(e, 165, qz / qn); putF(e, 166, qw / qn);
        }
    }
    __syncthreads();

    // --- MFMA phase: wave w owns N columns [w*32, w*32+32) ---
    const int arow = lane & 15, agrp = lane >> 4;
    const int ng0 = w * 2;
    f32x4 acc[2][2];
#pragma unroll
    for (int m = 0; m < 2; ++m)
#pragma unroll
        for (int n = 0; n < 2; ++n) acc[m][n] = (f32x4){0.f, 0.f, 0.f, 0.f};

    const bf16x8* WhF = (const bf16x8*)Wh;
    const bf16x8* WlF = (const bf16x8*)Wl;

#pragma unroll
    for (int kt = 0; kt < NKT; ++kt) {
        const int kof = kt * 32 + agrp * 8;
        bf16x8 a0 = *(const bf16x8*)&Fh[arow][kof];
        bf16x8 a1 = *(const bf16x8*)&Fh[16 + arow][kof];
        bf16x8 b0h = WhF[(kt * 8 + ng0) * 64 + lane];
        bf16x8 b1h = WhF[(kt * 8 + ng0 + 1) * 64 + lane];
        bf16x8 b0l = WlF[(kt * 8 + ng0) * 64 + lane];
        bf16x8 b1l = WlF[(kt * 8 + ng0 + 1) * 64 + lane];

        acc[0][0] = __builtin_amdgcn_mfma_f32_16x16x32_bf16(a0, b0h, acc[0][0], 0, 0, 0);
        acc[0][0] = __builtin_amdgcn_mfma_f32_16x16x32_bf16(a0, b0l, acc[0][0], 0, 0, 0);
        acc[0][1] = __builtin_amdgcn_mfma_f32_16x16x32_bf16(a0, b1h, acc[0][1], 0, 0, 0);
        acc[0][1] = __builtin_amdgcn_mfma_f32_16x16x32_bf16(a0, b1l, acc[0][1], 0, 0, 0);
        acc[1][0] = __builtin_amdgcn_mfma_f32_16x16x32_bf16(a1, b0h, acc[1][0], 0, 0, 0);
        acc[1][0] = __builtin_amdgcn_mfma_f32_16x16x32_bf16(a1, b0l, acc[1][0], 0, 0, 0);
        acc[1][1] = __builtin_amdgcn_mfma_f32_16x16x32_bf16(a1, b1h, acc[1][1], 0, 0, 0);
        acc[1][1] = __builtin_amdgcn_mfma_f32_16x16x32_bf16(a1, b1l, acc[1][1], 0, 0, 0);
    }

    // --- LN stats from accumulators: per-wave partials + 4-level arow reduce ---
    float ps[2][4], pq[2][4];
#pragma unroll
    for (int m = 0; m < 2; ++m)
#pragma unroll
        for (int r = 0; r < 4; ++r) {
            float v0 = acc[m][0][r], v1 = acc[m][1][r];
            ps[m][r] = v0 + v1;
            pq[m][r] = v0 * v0 + v1 * v1;
        }
#pragma unroll
    for (int off = 1; off < 16; off <<= 1) {
#pragma unroll
        for (int m = 0; m < 2; ++m)
#pragma unroll
            for (int r = 0; r < 4; ++r) {
                ps[m][r] += __shfl_xor(ps[m][r], off);
                pq[m][r] += __shfl_xor(pq[m][r], off);
            }
    }
    if (arow == 0) {
#pragma unroll
        for (int m = 0; m < 2; ++m)
#pragma unroll
            for (int r = 0; r < 4; ++r) {
                int me = m * 16 + agrp * 4 + r;
                Ssum[me][w] = ps[m][r];
                Ssq[me][w] = pq[m][r];
            }
    }
    __syncthreads();
    if (tid < 32) {
        float s = Ssum[tid][0] + Ssum[tid][1] + Ssum[tid][2] + Ssum[tid][3];
        float q = Ssq[tid][0] + Ssq[tid][1] + Ssq[tid][2] + Ssq[tid][3];
        float mean = s * (1.f / 128.f);
        float var = q * (1.f / 128.f) - mean * mean;
        Mstat[tid] = make_float2(mean, 1.f / sqrtf(var + 1e-5f));
    }
    __syncthreads();

    // --- normalize in-register + direct global store ---
    float gg[2], bb[2];
#pragma unroll
    for (int n = 0; n < 2; ++n) {
        int ce = (ng0 + n) * 16 + arow;
        gg[n] = ln_g[ce];
        bb[n] = ln_b[ce];
    }
#pragma unroll
    for (int m = 0; m < 2; ++m)
#pragma unroll
        for (int r = 0; r < 4; ++r) {
            int me = m * 16 + agrp * 4 + r;
            if (me >= KNB) continue;
            float2 st = Mstat[me];
            size_t base = ((size_t)row * KNB + me) * NC;
#pragma unroll
            for (int n = 0; n < 2; ++n) {
                int ce = (ng0 + n) * 16 + arow;
                outE[base + ce] = (acc[m][n][r] - st.x) * st.y * gg[n] + bb[n];
            }
        }
}

// ---------------------------------------------------------------------------
extern "C" void kernel_launch(void* const* d_in, const int* in_sizes, int n_in,
                              void* d_out, int out_size, void* d_ws, size_t ws_size,
                              hipStream_t stream) {
    const float* Ca     = (const float*)d_in[0];
    const float* mask   = (const float*)d_in[1];
    const int*   ridx   = (const int*)d_in[2];
    const int*   clab   = (const int*)d_in[3];
    const float* pos_W  = (const float*)d_in[4];
    const float* pos_b  = (const float*)d_in[5];
    const float* edge_W = (const float*)d_in[6];
    const float* ln_g   = (const float*)d_in[7];
    const float* ln_b   = (const float*)d_in[8];

    float* outE  = (float*)d_out;
    float* EidxF = outE + (size_t)Bc * Lc * KNB * NC;   // output 1 (as float values)

    float* Dn    = (float*)d_ws;                           // B*L*30 f32
    float* Omat  = Dn + (size_t)Bc * Lc * KNB;             // B*L*9 f32
    int*   EidxI = (int*)(Omat + (size_t)Bc * Lc * 9);     // B*L*30 i32
    unsigned short* Wh = (unsigned short*)(EidxI + (size_t)Bc * Lc * KNB);
    unsigned short* Wl = Wh + (size_t)NKT * 8 * 64 * 8;    // 24576 each

    const int rows = Bc * Lc;
    pack_kernel<<<12, 256, 0, stream>>>(edge_W, Wh, Wl);
    topk_kernel<<<rows, 256, 0, stream>>>(Ca, mask, Dn, EidxF, EidxI);
    orient_kernel<<<(rows + 255) / 256, 256, 0, stream>>>(Ca, Omat);
    edge_kernel<<<rows, 256, 0, stream>>>(Ca, ridx, clab, pos_W, pos_b, Wh, Wl,
                                          ln_g, ln_b, Dn, EidxI, Omat, outE);
}